// Round 12
// baseline (231.985 us; speedup 1.0000x reference)
//
#include <hip/hip_runtime.h>
#include <hip/hip_bf16.h>
#include <math.h>

typedef __bf16 bf16_t;
typedef __attribute__((ext_vector_type(8))) __bf16 bf16x8;
typedef __attribute__((ext_vector_type(4))) __bf16 bf16x4;
typedef __attribute__((ext_vector_type(4))) float f32x4;

#define BATCH 8
#define NTOK 1024
#define NEDGE 16384
#define CAP 96   // max entries per row (deg ~ Poisson(32); P(deg>96) < 1e-20)

// ---------------- async global->LDS (16B per lane, wave-uniform LDS base) ----------------
__device__ __forceinline__ void gload_lds16(const void* g, void* l) {
  __builtin_amdgcn_global_load_lds(
      (const __attribute__((address_space(1))) unsigned int*)(uintptr_t)g,
      (__attribute__((address_space(3))) unsigned int*)(unsigned int)(uintptr_t)l,
      16, 0, 0);
}

// ---------------- fused: f32->bf16 cvt for H + weights; blocks <8 also zero cnt ----------------
__global__ void k_pre(int4* __restrict__ cnt,
                      const float* __restrict__ H, const float* __restrict__ Wqkv,
                      const float* __restrict__ Wo, const float* __restrict__ W1,
                      const float* __restrict__ W2, bf16_t* __restrict__ xb,
                      bf16_t* __restrict__ wqkvb, bf16_t* __restrict__ wob,
                      bf16_t* __restrict__ w1b, bf16_t* __restrict__ w2b) {
  int i = blockIdx.x * 256 + threadIdx.x;   // float4-quad index
  if (blockIdx.x < 8) {
    int4 z = {0, 0, 0, 0};
    cnt[i] = z;                             // 8 blocks x 256 x int4 = 8192 ints
  }
  const float* s; bf16_t* d; int off;
  if (i < 524288)      { s = H;    d = xb;    off = i; }
  else if (i < 622592) { s = Wqkv; d = wqkvb; off = i - 524288; }
  else if (i < 655360) { s = Wo;   d = wob;   off = i - 622592; }
  else if (i < 786432) { s = W1;   d = w1b;   off = i - 655360; }
  else if (i < 917504) { s = W2;   d = w2b;   off = i - 786432; }
  else return;
  float4 v = ((const float4*)s)[off];
  bf16x4 o;
  o[0] = (bf16_t)v.x; o[1] = (bf16_t)v.y; o[2] = (bf16_t)v.z; o[3] = (bf16_t)v.w;
  ((bf16x4*)d)[off] = o;
}

// ---------------- edge scatter: packed (prio<<10|col) appended to per-row lists ----------------
__global__ void k_scatter2(const int* __restrict__ ei, int* __restrict__ cnt,
                           int* __restrict__ ent) {
  int idx = blockIdx.x * 256 + threadIdx.x;
  if (idx >= BATCH * NEDGE) return;
  int b = idx >> 14;
  int e = idx & (NEDGE - 1);
  const int* eb = ei + (size_t)b * 2 * NEDGE;
  int r = eb[e], c = eb[NEDGE + e];
  int rowr = (b << 10) + r, rowc = (b << 10) + c;
  int q = atomicAdd(cnt + rowr, 1);
  if (q < CAP) ent[rowr * CAP + q] = ((e + 1) << 10) | c;
  q = atomicAdd(cnt + rowc, 1);
  if (q < CAP) ent[rowc * CAP + q] = ((NEDGE + e + 1) << 10) | r;
}

// ---------------- CSR build v2: dedup per row in LDS, canonical ascending-col order ----------------
__global__ __launch_bounds__(256) void k_build2(
    const int* __restrict__ cnt, const int* __restrict__ ent,
    const float* __restrict__ mptr,
    int* __restrict__ nbcol, float* __restrict__ nbval, int* __restrict__ nbcnt) {
  const int w = threadIdx.x >> 6;
  const int l = threadIdx.x & 63;
  const int row = blockIdx.x * 4 + w;   // b*1024 + i
  const int i = row & 1023;
  const int b = row >> 10;
  __shared__ int sE[4][CAP];
  __shared__ int sW[4][CAP];
  const int n = min(cnt[row], CAP);
  for (int j = l; j < n; j += 64) sE[w][j] = ent[(size_t)row * CAP + j];
  __syncthreads();

  bool dcov_l = false;
  bool win[2] = {false, false};
  int myc[2], myp[2];
#pragma unroll
  for (int s = 0; s < 2; ++s) {
    int k = s * 64 + l;
    if (k < n) {
      int pk = sE[w][k], ck = pk & 1023;
      myc[s] = ck; myp[s] = pk;
      bool wn = true;
      for (int j = 0; j < n; ++j) {
        int pj = sE[w][j];
        if ((pj & 1023) == ck && pj > pk) wn = false;
      }
      win[s] = wn;
      sW[w][k] = wn ? 1 : 0;
      if (ck == i) dcov_l = true;
    }
  }
  const bool dcov = __any(dcov_l);
  unsigned long long m0 = __ballot(win[0]);
  unsigned long long m1 = __ballot(win[1]);
  if (l == 0) nbcnt[row] = __popcll(m0) + __popcll(m1) + (dcov ? 0 : 1);

#pragma unroll
  for (int s = 0; s < 2; ++s) {
    int k = s * 64 + l;
    if (k < n && win[s]) {
      int pos = 0;
      for (int j = 0; j < n; ++j)
        if (sW[w][j] && (sE[w][j] & 1023) < myc[s]) ++pos;
      if (!dcov && i < myc[s]) ++pos;
      int e = ((myp[s] >> 10) - 1) & (NEDGE - 1);
      float v = logf(mptr[(size_t)b * NEDGE + e] + 1e-9f);
      if (pos < CAP) {
        nbcol[(size_t)row * CAP + pos] = myc[s];
        nbval[(size_t)row * CAP + pos] = v;
      }
    }
  }
  if (!dcov && l == 0) {   // virtual diagonal (value 0)
    int pos = 0;
    for (int j = 0; j < n; ++j)
      if (sW[w][j] && (sE[w][j] & 1023) < i) ++pos;
    nbcol[(size_t)row * CAP + pos] = i;
    nbval[(size_t)row * CAP + pos] = 0.f;
  }
}

// ---------------- GEMM BMx128 tile, dbuf LDS, race-free single-barrier pipeline ----------------
// loop: stage(t+1, buf^1) -> compute(t, buf) -> vmcnt(0) -> barrier.
// EPI 1: gelu -> bf16 out. EPI 3: plain bf16 out.  BM in {64,128}.
template <int EPI, int BM>
__global__ __launch_bounds__(256) void gemm_bt(
    const bf16_t* __restrict__ A, const bf16_t* __restrict__ Bw,
    const float* __restrict__ bias, bf16_t* __restrict__ Cb,
    int M, int N, int K) {
  constexpr int MI = BM / 32;            // acc rows per wave
  __shared__ bf16_t As[2][BM * 64];
  __shared__ bf16_t Bs[2][128 * 64];
  const int t = threadIdx.x;
  const int l = t & 63;
  const int w = t >> 6;
  const int wr = w >> 1, wc = w & 1;     // 2x2 waves over BM rows x 128 cols
  const int bm = blockIdx.y * BM, bn = blockIdx.x * 128;

  f32x4 acc[MI][4] = {};

  auto stage = [&](int buf, int k0) {
#pragma unroll
    for (int i = 0; i < BM / 32; ++i) {  // A: BM x 64 elems
      int idx = i * 2048 + t * 8;
      int row = idx >> 6, col = idx & 63;
      gload_lds16(A + (size_t)(bm + row) * K + (k0 + col), (void*)(&As[buf][0] + i * 2048 + w * 512));
    }
#pragma unroll
    for (int i = 0; i < 4; ++i) {        // B: 128 x 64 elems
      int idx = i * 2048 + t * 8;
      int row = idx >> 6, col = idx & 63;
      gload_lds16(Bw + (size_t)(bn + row) * K + (k0 + col), (void*)(&Bs[buf][0] + i * 2048 + w * 512));
    }
  };

  const int nt = K >> 6;
  stage(0, 0);
  asm volatile("s_waitcnt vmcnt(0)" ::: "memory");
  __syncthreads();
  for (int kt = 0; kt < nt; ++kt) {
    const int cur = kt & 1;
    if (kt + 1 < nt) stage(cur ^ 1, (kt + 1) << 6);   // loads fly during compute
#pragma unroll
    for (int kk = 0; kk < 2; ++kk) {
      bf16x8 af[MI], bfr[4];
#pragma unroll
      for (int mi = 0; mi < MI; ++mi)
        af[mi] = *(const bf16x8*)(&As[cur][0] + (wr * (BM / 2) + mi * 16 + (l & 15)) * 64 + kk * 32 + (l >> 4) * 8);
#pragma unroll
      for (int ni = 0; ni < 4; ++ni)
        bfr[ni] = *(const bf16x8*)(&Bs[cur][0] + (wc * 64 + ni * 16 + (l & 15)) * 64 + kk * 32 + (l >> 4) * 8);
#pragma unroll
      for (int mi = 0; mi < MI; ++mi)
#pragma unroll
        for (int ni = 0; ni < 4; ++ni)
          acc[mi][ni] = __builtin_amdgcn_mfma_f32_16x16x32_bf16(af[mi], bfr[ni], acc[mi][ni], 0, 0, 0);
    }
    asm volatile("s_waitcnt vmcnt(0)" ::: "memory");
    __syncthreads();
  }

  const int r0 = (l >> 4) * 4;   // C/D: row=(lane>>4)*4+reg, col=lane&15
  const int cc = l & 15;
#pragma unroll
  for (int mi = 0; mi < MI; ++mi) {
#pragma unroll
    for (int ni = 0; ni < 4; ++ni) {
      int col = bn + wc * 64 + ni * 16 + cc;
      float bv = bias[col];
#pragma unroll
      for (int r = 0; r < 4; ++r) {
        int row = bm + wr * (BM / 2) + mi * 16 + r0 + r;
        float v = acc[mi][ni][r] + bv;
        if (EPI == 1)
          v = 0.5f * v * (1.f + erff(v * 0.70710678118654752f));   // exact GELU
        Cb[(size_t)row * N + col] = (bf16_t)v;
      }
    }
  }
}

// ---------------- fused attention + out-projection + residual + LN1 ----------------
// grid 512 (XCD-swizzled: batch = bid&7), block = 16 rows. Wave w: rows bm+w*4..+3 serial.
__global__ __launch_bounds__(256) void k_attn_oproj(
    const bf16_t* __restrict__ qkvb,
    const int* __restrict__ nbcol, const float* __restrict__ nbval,
    const int* __restrict__ nbcnt,
    const bf16_t* __restrict__ Wo, const float* __restrict__ bo,
    const bf16_t* __restrict__ residb,
    const float* __restrict__ lnw, const float* __restrict__ lnb,
    bf16_t* __restrict__ xbout) {
  __shared__ __align__(16) char smem[57856];
  bf16_t* Bs    = (bf16_t*)smem;             // [256][64] single-buffer k-tile (32 KB)
  bf16_t* ao    = (bf16_t*)(smem + 32768);   // [16][264] attn out (stride 264 -> 2-way-free frags)
  float*  s_s   = (float*)(smem + 41216);    // [4][8][97] scores
  int*    s_col = (int*)(smem + 53632);      // [4][96]
  float*  s_bia = (float*)(smem + 55168);    // [4][96]
  float*  E     = (float*)(smem + 41216);    // [16][258] f32, aliases attn buffers (dead)
  const int t = threadIdx.x, l = t & 63, w = t >> 6;
  const int b = blockIdx.x & 7;              // XCD-swizzle: one batch per XCD
  const int bm = (b << 10) + (blockIdx.x >> 3) * 16;

  auto stageB = [&](int k0) {
#pragma unroll
    for (int i = 0; i < 8; ++i) {
      int rr = (w * 8 + i) * 8 + (l >> 3), col = (l & 7) * 8;
      gload_lds16(Wo + (size_t)rr * 256 + (k0 + col), (void*)(Bs + (w * 8 + i) * 512));
    }
  };
  stageB(0);   // W_o tile 0 flies during the whole attention phase

  const float scale = 0.17677669529663687f;   // 1/sqrt(32)
  const int h1 = l & 7;
  for (int rr = 0; rr < 4; ++rr) {
    const int row = bm + w * 4 + rr;
    const int deg = nbcnt[row];
    asm volatile("s_waitcnt lgkmcnt(0)" ::: "memory");
    for (int j = l; j < deg; j += 64) {
      s_col[w * 96 + j] = nbcol[(size_t)row * CAP + j];
      s_bia[w * 96 + j] = nbval[(size_t)row * CAP + j];
    }
    float q[32];
    {
      const bf16x8* qp = (const bf16x8*)(qkvb + (size_t)row * 768 + h1 * 32);
#pragma unroll
      for (int u = 0; u < 4; ++u) {
        bf16x8 t8 = qp[u];
#pragma unroll
        for (int j = 0; j < 8; ++j) q[u * 8 + j] = (float)t8[j];
      }
    }
    asm volatile("s_waitcnt lgkmcnt(0)" ::: "memory");

    const int nit = (deg + 7) >> 3;
    float mx = -INFINITY;
    for (int it = 0; it < nit; ++it) {
      int idx = it * 8 + (l >> 3);
      float sc = -INFINITY;
      if (idx < deg) {
        int col = s_col[w * 96 + idx];
        const bf16x8* kr = (const bf16x8*)(qkvb + ((size_t)((b << 10) + col)) * 768 + 256 + h1 * 32);
        float d = 0.f;
#pragma unroll
        for (int u = 0; u < 4; ++u) {
          bf16x8 kv = kr[u];
#pragma unroll
          for (int j = 0; j < 8; ++j) d += (float)kv[j] * q[u * 8 + j];
        }
        sc = d * scale + s_bia[w * 96 + idx];
        s_s[(w * 8 + h1) * 97 + idx] = sc;
      }
      mx = fmaxf(mx, sc);
    }
#pragma unroll
    for (int o = 8; o < 64; o <<= 1) mx = fmaxf(mx, __shfl_xor(mx, o));
    asm volatile("s_waitcnt lgkmcnt(0)" ::: "memory");
    float lsum = 0.f;
    for (int it = 0; it < nit; ++it) {
      int idx = it * 8 + (l >> 3);
      if (idx < deg) {
        float p = __expf(s_s[(w * 8 + h1) * 97 + idx] - mx);
        s_s[(w * 8 + h1) * 97 + idx] = p;
        lsum += p;
      }
    }
#pragma unroll
    for (int o = 8; o < 64; o <<= 1) lsum += __shfl_xor(lsum, o);
    const int h3 = l >> 3;
    float den = __shfl(lsum, h3);
    asm volatile("s_waitcnt lgkmcnt(0)" ::: "memory");
    float a0 = 0.f, a1 = 0.f, a2 = 0.f, a3 = 0.f;
    const bf16_t* vbase = qkvb + ((size_t)(b << 10)) * 768 + 512 + l * 4;
#pragma unroll 4
    for (int idx = 0; idx < deg; ++idx) {
      float p = s_s[(w * 8 + h3) * 97 + idx];
      bf16x4 vv = *(const bf16x4*)(vbase + (size_t)s_col[w * 96 + idx] * 768);
      a0 += p * (float)vv[0]; a1 += p * (float)vv[1];
      a2 += p * (float)vv[2]; a3 += p * (float)vv[3];
    }
    float rden = 1.f / den;
    bf16x4 o4;
    o4[0] = (bf16_t)(a0 * rden); o4[1] = (bf16_t)(a1 * rden);
    o4[2] = (bf16_t)(a2 * rden); o4[3] = (bf16_t)(a3 * rden);
    *(bf16x4*)(ao + (w * 4 + rr) * 264 + l * 4) = o4;
  }
  asm volatile("s_waitcnt vmcnt(0) lgkmcnt(0)" ::: "memory");
  __syncthreads();

  // out-projection: C[16][256] = ao @ Wo^T, K=256 in 4 tiles
  f32x4 acc[4] = {};
  for (int kt = 0; kt < 4; ++kt) {
#pragma unroll
    for (int kk = 0; kk < 2; ++kk) {
      bf16x8 af = *(const bf16x8*)(ao + (l & 15) * 264 + kt * 64 + kk * 32 + (l >> 4) * 8);
#pragma unroll
      for (int ni = 0; ni < 4; ++ni) {
        bf16x8 bfr = *(const bf16x8*)(Bs + (w * 64 + ni * 16 + (l & 15)) * 64 + kk * 32 + (l >> 4) * 8);
        acc[ni] = __builtin_amdgcn_mfma_f32_16x16x32_bf16(af, bfr, acc[ni], 0, 0, 0);
      }
    }
    __syncthreads();
    if (kt < 3) {
      stageB((kt + 1) * 64);
      asm volatile("s_waitcnt vmcnt(0)" ::: "memory");
      __syncthreads();
    }
  }

  const int r0 = (l >> 4) * 4;
  const int cc = l & 15;
#pragma unroll
  for (int ni = 0; ni < 4; ++ni) {
    int col = w * 64 + ni * 16 + cc;
    float bv = bo[col];
#pragma unroll
    for (int r = 0; r < 4; ++r)
      E[(r0 + r) * 258 + col] = acc[ni][r] + bv;
  }
  __syncthreads();

  const int row = t >> 4;
  const int sub = t & 15;
  const float* ep = E + row * 258 + sub * 16;
  const bf16_t* rp = residb + (size_t)(bm + row) * 256 + sub * 16;
  float v[16];
  float s = 0.f;
#pragma unroll
  for (int j = 0; j < 4; ++j) {
    float4 a4 = ((const float4*)ep)[j];
    bf16x4 r4 = ((const bf16x4*)rp)[j];
    v[j * 4 + 0] = a4.x + (float)r4[0]; v[j * 4 + 1] = a4.y + (float)r4[1];
    v[j * 4 + 2] = a4.z + (float)r4[2]; v[j * 4 + 3] = a4.w + (float)r4[3];
    s += v[j * 4 + 0] + v[j * 4 + 1] + v[j * 4 + 2] + v[j * 4 + 3];
  }
#pragma unroll
  for (int o = 1; o < 16; o <<= 1) s += __shfl_xor(s, o);
  float mu = s * (1.f / 256.f);
  float e2 = 0.f;
#pragma unroll
  for (int j = 0; j < 16; ++j) { float d = v[j] - mu; e2 += d * d; }
#pragma unroll
  for (int o = 1; o < 16; o <<= 1) e2 += __shfl_xor(e2, o);
  float rs = rsqrtf(e2 * (1.f / 256.f) + 1e-5f);
  bf16_t* xbo = xbout + (size_t)(bm + row) * 256 + sub * 16;
#pragma unroll
  for (int j = 0; j < 4; ++j) {
    float4 w4 = ((const float4*)(lnw + sub * 16))[j];
    float4 b4 = ((const float4*)(lnb + sub * 16))[j];
    bf16x4 ob;
    ob[0] = (bf16_t)((v[j * 4 + 0] - mu) * rs * w4.x + b4.x);
    ob[1] = (bf16_t)((v[j * 4 + 1] - mu) * rs * w4.y + b4.y);
    ob[2] = (bf16_t)((v[j * 4 + 2] - mu) * rs * w4.z + b4.z);
    ob[3] = (bf16_t)((v[j * 4 + 3] - mu) * rs * w4.w + b4.w);
    ((bf16x4*)xbo)[j] = ob;
  }
}

// ---------------- ff2 + bias + bf16-residual + LayerNorm, v2 ----------------
// K=1024 fixed. A staged ONCE in padded LDS [16][1032] (bank-aliasing 2-way = free).
// B (W2): global -> VGPR direct (each B element used by exactly one wave, once) —
// 3-slot register rotation, fully unrolled K-loop, ZERO barriers in the loop.
// FIN=0: y -> bf16 xbout. FIN=1: additionally lnf(y) -> f32 outf (d_out).
template <int FIN>
__global__ __launch_bounds__(256) void gemm_ln(
    const bf16_t* __restrict__ A, const bf16_t* __restrict__ Bw,
    const float* __restrict__ bias, const bf16_t* __restrict__ residb,
    const float* __restrict__ lnw, const float* __restrict__ lnb,
    const float* __restrict__ lnfw, const float* __restrict__ lnfb,
    bf16_t* __restrict__ xbout, float* __restrict__ outf) {
  constexpr int K = 1024, NT = 16;
  __shared__ __align__(16) char smem[33024];   // [16][1032] bf16
  bf16_t* As = (bf16_t*)smem;
  float*  E  = (float*)smem;                   // [16][258] f32, aliases As after K-loop
  const int t = threadIdx.x;
  const int l = t & 63;
  const int w = t >> 6;
  const int bm = blockIdx.x * 16;

  // reg-stage A -> padded LDS (16 rows x 1024, stride 1032)
#pragma unroll
  for (int c = 0; c < 8; ++c) {
    int f = t + c * 256;              // 16B-chunk id, 2048 total
    int row = f >> 7, c16 = f & 127;
    bf16x8 v = *(const bf16x8*)(A + (size_t)(bm + row) * K + c16 * 8);
    *(bf16x8*)(As + row * 1032 + c16 * 8) = v;
  }
  __syncthreads();

  // per-wave B pipeline: depth-2 prefetch, 3 register slots (all indices compile-time)
  f32x4 acc[4] = {};
  bf16x8 breg[3][8];
  const bf16_t* bbase = Bw + (size_t)(w * 64 + (l & 15)) * K + (l >> 4) * 8;
#define LOADB(slot, kt)                                                        \
  {                                                                            \
    _Pragma("unroll")                                                          \
    for (int ni = 0; ni < 4; ++ni)                                             \
      _Pragma("unroll")                                                        \
      for (int kk = 0; kk < 2; ++kk)                                           \
        breg[slot][ni * 2 + kk] =                                              \
            *(const bf16x8*)(bbase + (size_t)(ni * 16) * K + (kt) * 64 + kk * 32); \
  }
  LOADB(0, 0)
  LOADB(1, 1)
#pragma unroll
  for (int kt = 0; kt < NT; ++kt) {
    if (kt + 2 < NT) LOADB((kt + 2) % 3, kt + 2)
#pragma unroll
    for (int kk = 0; kk < 2; ++kk) {
      bf16x8 af = *(const bf16x8*)(As + (l & 15) * 1032 + kt * 64 + kk * 32 + (l >> 4) * 8);
#pragma unroll
      for (int ni = 0; ni < 4; ++ni)
        acc[ni] = __builtin_amdgcn_mfma_f32_16x16x32_bf16(af, breg[kt % 3][ni * 2 + kk], acc[ni], 0, 0, 0);
    }
  }
#undef LOADB
  __syncthreads();   // all LDS A-reads done before E (aliases As) is written

  // stash C+bias into LDS f32 [16][258]
  const int r0 = (l >> 4) * 4;
  const int cc = l & 15;
#pragma unroll
  for (int ni = 0; ni < 4; ++ni) {
    int col = w * 64 + ni * 16 + cc;
    float bv = bias[col];
#pragma unroll
    for (int r = 0; r < 4; ++r)
      E[(r0 + r) * 258 + col] = acc[ni][r] + bv;
  }
  __syncthreads();

  // LN: 16 threads per row, 16 cols per thread; residual from bf16
  const int row = t >> 4;
  const int sub = t & 15;
  const float* ep = E + row * 258 + sub * 16;
  const bf16_t* rp = residb + (size_t)(bm + row) * 256 + sub * 16;
  float v[16];
  float s = 0.f;
#pragma unroll
  for (int j = 0; j < 4; ++j) {
    float4 a4 = ((const float4*)ep)[j];
    bf16x4 r4 = ((const bf16x4*)rp)[j];
    v[j * 4 + 0] = a4.x + (float)r4[0]; v[j * 4 + 1] = a4.y + (float)r4[1];
    v[j * 4 + 2] = a4.z + (float)r4[2]; v[j * 4 + 3] = a4.w + (float)r4[3];
    s += v[j * 4 + 0] + v[j * 4 + 1] + v[j * 4 + 2] + v[j * 4 + 3];
  }
#pragma unroll
  for (int o = 1; o < 16; o <<= 1) s += __shfl_xor(s, o);
  float mu = s * (1.f / 256.f);
  float e2 = 0.f;
#pragma unroll
  for (int j = 0; j < 16; ++j) { float d = v[j] - mu; e2 += d * d; }
#pragma unroll
  for (int o = 1; o < 16; o <<= 1) e2 += __shfl_xor(e2, o);
  float rs = rsqrtf(e2 * (1.f / 256.f) + 1e-5f);
  float y[16];
#pragma unroll
  for (int j = 0; j < 4; ++j) {
    float4 w4 = ((const float4*)(lnw + sub * 16))[j];
    float4 b4 = ((const float4*)(lnb + sub * 16))[j];
    y[j * 4 + 0] = (v[j * 4 + 0] - mu) * rs * w4.x + b4.x;
    y[j * 4 + 1] = (v[j * 4 + 1] - mu) * rs * w4.y + b4.y;
    y[j * 4 + 2] = (v[j * 4 + 2] - mu) * rs * w4.z + b4.z;
    y[j * 4 + 3] = (v[j * 4 + 3] - mu) * rs * w4.w + b4.w;
  }
  if (FIN == 0) {
    bf16_t* xbo = xbout + (size_t)(bm + row) * 256 + sub * 16;
#pragma unroll
    for (int j = 0; j < 4; ++j) {
      bf16x4 ob;
      ob[0] = (bf16_t)y[j * 4 + 0]; ob[1] = (bf16_t)y[j * 4 + 1];
      ob[2] = (bf16_t)y[j * 4 + 2]; ob[3] = (bf16_t)y[j * 4 + 3];
      ((bf16x4*)xbo)[j] = ob;
    }
  } else {
    float s2 = 0.f;
#pragma unroll
    for (int j = 0; j < 16; ++j) s2 += y[j];
#pragma unroll
    for (int o = 1; o < 16; o <<= 1) s2 += __shfl_xor(s2, o);
    float mu2 = s2 * (1.f / 256.f);
    float q2 = 0.f;
#pragma unroll
    for (int j = 0; j < 16; ++j) { float d = y[j] - mu2; q2 += d * d; }
#pragma unroll
    for (int o = 1; o < 16; o <<= 1) q2 += __shfl_xor(q2, o);
    float rs2 = rsqrtf(q2 * (1.f / 256.f) + 1e-5f);
    float* xo = outf + (size_t)(bm + row) * 256 + sub * 16;
#pragma unroll
    for (int j = 0; j < 4; ++j) {
      float4 w4 = ((const float4*)(lnfw + sub * 16))[j];
      float4 b4 = ((const float4*)(lnfb + sub * 16))[j];
      float4 o4 = {(y[j * 4 + 0] - mu2) * rs2 * w4.x + b4.x,
                   (y[j * 4 + 1] - mu2) * rs2 * w4.y + b4.y,
                   (y[j * 4 + 2] - mu2) * rs2 * w4.z + b4.z,
                   (y[j * 4 + 3] - mu2) * rs2 * w4.w + b4.w};
      ((float4*)xo)[j] = o4;
    }
  }
}

extern "C" void kernel_launch(void* const* d_in, const int* in_sizes, int n_in,
                              void* d_out, int out_size, void* d_ws, size_t ws_size,
                              hipStream_t stream) {
  const float* H    = (const float*)d_in[0];
  const int*   ei   = (const int*)d_in[1];
  const float* m    = (const float*)d_in[2];
  const float* Wqkv = (const float*)d_in[3];
  const float* bqkv = (const float*)d_in[4];
  const float* Wo   = (const float*)d_in[5];
  const float* bo   = (const float*)d_in[6];
  const float* ln1w = (const float*)d_in[7];
  const float* ln1b = (const float*)d_in[8];
  const float* W1   = (const float*)d_in[9];
  const float* b1   = (const float*)d_in[10];
  const float* W2   = (const float*)d_in[11];
  const float* b2   = (const float*)d_in[12];
  const float* ln2w = (const float*)d_in[13];
  const float* ln2b = (const float*)d_in[14];
  const float* lnfw = (const float*)d_in[15];
  const float* lnfb = (const float*)d_in[16];

  char* ws = (char*)d_ws;
  size_t off = 0;
  auto alloc = [&](size_t bytes) {
    void* p = ws + off;
    off += (bytes + 255) & ~(size_t)255;
    return p;
  };

  int*    cnt   = (int*)alloc((size_t)BATCH * NTOK * 4);
  int*    ent   = (int*)alloc((size_t)BATCH * NTOK * CAP * 4);
  int*    nbcol = (int*)alloc((size_t)BATCH * NTOK * CAP * 4);
  float*  nbval = (float*)alloc((size_t)BATCH * NTOK * CAP * 4);
  int*    nbcnt = (int*)alloc((size_t)BATCH * NTOK * 4);
  bf16_t* qkvb  = (bf16_t*)alloc((size_t)8192 * 768 * 2);
  bf16_t* wqkvb = (bf16_t*)alloc((size_t)2 * 768 * 256 * 2);
  bf16_t* wob   = (bf16_t*)alloc((size_t)2 * 256 * 256 * 2);
  bf16_t* w1b   = (bf16_t*)alloc((size_t)2 * 1024 * 256 * 2);
  bf16_t* w2b   = (bf16_t*)alloc((size_t)2 * 256 * 1024 * 2);
  bf16_t* xb    = (bf16_t*)alloc((size_t)8192 * 256 * 2);   // layer input x (bf16)
  bf16_t* x1b   = (bf16_t*)alloc((size_t)8192 * 256 * 2);   // after ln1
  bf16_t* ffb   = (bf16_t*)alloc((size_t)8192 * 1024 * 2);

  k_pre<<<3584, 256, 0, stream>>>((int4*)cnt, H, Wqkv, Wo, W1, W2,
                                  xb, wqkvb, wob, w1b, w2b);
  k_scatter2<<<(BATCH * NEDGE + 255) / 256, 256, 0, stream>>>(ei, cnt, ent);
  k_build2<<<BATCH * NTOK / 4, 256, 0, stream>>>(cnt, ent, m, nbcol, nbval, nbcnt);

  for (int lyr = 0; lyr < 2; ++lyr) {
    gemm_bt<3, 64><<<dim3(768 / 128, 8192 / 64), 256, 0, stream>>>(
        xb, wqkvb + (size_t)lyr * 768 * 256, bqkv + lyr * 768, qkvb, 8192, 768, 256);
    k_attn_oproj<<<512, 256, 0, stream>>>(
        qkvb, nbcol, nbval, nbcnt,
        wob + (size_t)lyr * 256 * 256, bo + lyr * 256, xb,
        ln1w + lyr * 256, ln1b + lyr * 256, x1b);
    gemm_bt<1, 128><<<dim3(1024 / 128, 8192 / 128), 256, 0, stream>>>(
        x1b, w1b + (size_t)lyr * 1024 * 256, b1 + lyr * 1024, ffb, 8192, 1024, 256);
    if (lyr == 0) {
      gemm_ln<0><<<512, 256, 0, stream>>>(
          ffb, w2b + (size_t)lyr * 256 * 1024, b2 + lyr * 256, x1b,
          ln2w + lyr * 256, ln2b + lyr * 256, nullptr, nullptr, xb, nullptr);
    } else {
      gemm_ln<1><<<512, 256, 0, stream>>>(
          ffb, w2b + (size_t)lyr * 256 * 1024, b2 + lyr * 256, x1b,
          ln2w + lyr * 256, ln2b + lyr * 256, lnfw, lnfb, nullptr, (float*)d_out);
    }
  }
}

// Round 13
// 195.327 us; speedup vs baseline: 1.1877x; 1.1877x over previous
//
#include <hip/hip_runtime.h>
#include <hip/hip_bf16.h>
#include <math.h>

typedef __bf16 bf16_t;
typedef __attribute__((ext_vector_type(8))) __bf16 bf16x8;
typedef __attribute__((ext_vector_type(4))) __bf16 bf16x4;
typedef __attribute__((ext_vector_type(4))) float f32x4;

#define BATCH 8
#define NTOK 1024
#define NEDGE 16384
#define CAP 96   // max entries per row (deg ~ Poisson(32); P(deg>96) < 1e-20)

// ---------------- async global->LDS (16B per lane, wave-uniform LDS base) ----------------
__device__ __forceinline__ void gload_lds16(const void* g, void* l) {
  __builtin_amdgcn_global_load_lds(
      (const __attribute__((address_space(1))) unsigned int*)(uintptr_t)g,
      (__attribute__((address_space(3))) unsigned int*)(unsigned int)(uintptr_t)l,
      16, 0, 0);
}

// ---------------- fused: f32->bf16 cvt for H + weights; blocks <8 also zero cnt ----------------
__global__ void k_pre(int4* __restrict__ cnt,
                      const float* __restrict__ H, const float* __restrict__ Wqkv,
                      const float* __restrict__ Wo, const float* __restrict__ W1,
                      const float* __restrict__ W2, bf16_t* __restrict__ xb,
                      bf16_t* __restrict__ wqkvb, bf16_t* __restrict__ wob,
                      bf16_t* __restrict__ w1b, bf16_t* __restrict__ w2b) {
  int i = blockIdx.x * 256 + threadIdx.x;   // float4-quad index
  if (blockIdx.x < 8) {
    int4 z = {0, 0, 0, 0};
    cnt[i] = z;                             // 8 blocks x 256 x int4 = 8192 ints
  }
  const float* s; bf16_t* d; int off;
  if (i < 524288)      { s = H;    d = xb;    off = i; }
  else if (i < 622592) { s = Wqkv; d = wqkvb; off = i - 524288; }
  else if (i < 655360) { s = Wo;   d = wob;   off = i - 622592; }
  else if (i < 786432) { s = W1;   d = w1b;   off = i - 655360; }
  else if (i < 917504) { s = W2;   d = w2b;   off = i - 786432; }
  else return;
  float4 v = ((const float4*)s)[off];
  bf16x4 o;
  o[0] = (bf16_t)v.x; o[1] = (bf16_t)v.y; o[2] = (bf16_t)v.z; o[3] = (bf16_t)v.w;
  ((bf16x4*)d)[off] = o;
}

// ---------------- edge scatter: packed (prio<<10|col) appended to per-row lists ----------------
__global__ void k_scatter2(const int* __restrict__ ei, int* __restrict__ cnt,
                           int* __restrict__ ent) {
  int idx = blockIdx.x * 256 + threadIdx.x;
  if (idx >= BATCH * NEDGE) return;
  int b = idx >> 14;
  int e = idx & (NEDGE - 1);
  const int* eb = ei + (size_t)b * 2 * NEDGE;
  int r = eb[e], c = eb[NEDGE + e];
  int rowr = (b << 10) + r, rowc = (b << 10) + c;
  int q = atomicAdd(cnt + rowr, 1);
  if (q < CAP) ent[rowr * CAP + q] = ((e + 1) << 10) | c;
  q = atomicAdd(cnt + rowc, 1);
  if (q < CAP) ent[rowc * CAP + q] = ((NEDGE + e + 1) << 10) | r;
}

// ---------------- CSR build v2: dedup per row in LDS, canonical ascending-col order ----------------
__global__ __launch_bounds__(256) void k_build2(
    const int* __restrict__ cnt, const int* __restrict__ ent,
    const float* __restrict__ mptr,
    int* __restrict__ nbcol, float* __restrict__ nbval, int* __restrict__ nbcnt) {
  const int w = threadIdx.x >> 6;
  const int l = threadIdx.x & 63;
  const int row = blockIdx.x * 4 + w;   // b*1024 + i
  const int i = row & 1023;
  const int b = row >> 10;
  __shared__ int sE[4][CAP];
  __shared__ int sW[4][CAP];
  const int n = min(cnt[row], CAP);
  for (int j = l; j < n; j += 64) sE[w][j] = ent[(size_t)row * CAP + j];
  __syncthreads();

  bool dcov_l = false;
  bool win[2] = {false, false};
  int myc[2], myp[2];
#pragma unroll
  for (int s = 0; s < 2; ++s) {
    int k = s * 64 + l;
    if (k < n) {
      int pk = sE[w][k], ck = pk & 1023;
      myc[s] = ck; myp[s] = pk;
      bool wn = true;
      for (int j = 0; j < n; ++j) {
        int pj = sE[w][j];
        if ((pj & 1023) == ck && pj > pk) wn = false;
      }
      win[s] = wn;
      sW[w][k] = wn ? 1 : 0;
      if (ck == i) dcov_l = true;
    }
  }
  const bool dcov = __any(dcov_l);
  unsigned long long m0 = __ballot(win[0]);
  unsigned long long m1 = __ballot(win[1]);
  if (l == 0) nbcnt[row] = __popcll(m0) + __popcll(m1) + (dcov ? 0 : 1);

#pragma unroll
  for (int s = 0; s < 2; ++s) {
    int k = s * 64 + l;
    if (k < n && win[s]) {
      int pos = 0;
      for (int j = 0; j < n; ++j)
        if (sW[w][j] && (sE[w][j] & 1023) < myc[s]) ++pos;
      if (!dcov && i < myc[s]) ++pos;
      int e = ((myp[s] >> 10) - 1) & (NEDGE - 1);
      float v = logf(mptr[(size_t)b * NEDGE + e] + 1e-9f);
      if (pos < CAP) {
        nbcol[(size_t)row * CAP + pos] = myc[s];
        nbval[(size_t)row * CAP + pos] = v;
      }
    }
  }
  if (!dcov && l == 0) {   // virtual diagonal (value 0)
    int pos = 0;
    for (int j = 0; j < n; ++j)
      if (sW[w][j] && (sE[w][j] & 1023) < i) ++pos;
    nbcol[(size_t)row * CAP + pos] = i;
    nbval[(size_t)row * CAP + pos] = 0.f;
  }
}

// ---------------- GEMM BMx128 tile, dbuf LDS, race-free single-barrier pipeline ----------------
// loop: stage(t+1, buf^1) -> compute(t, buf) -> vmcnt(0) -> barrier.
// EPI 1: gelu -> bf16 out. EPI 3: plain bf16 out.  BM in {64,128}.
template <int EPI, int BM>
__global__ __launch_bounds__(256) void gemm_bt(
    const bf16_t* __restrict__ A, const bf16_t* __restrict__ Bw,
    const float* __restrict__ bias, bf16_t* __restrict__ Cb,
    int M, int N, int K) {
  constexpr int MI = BM / 32;            // acc rows per wave
  __shared__ bf16_t As[2][BM * 64];
  __shared__ bf16_t Bs[2][128 * 64];
  const int t = threadIdx.x;
  const int l = t & 63;
  const int w = t >> 6;
  const int wr = w >> 1, wc = w & 1;     // 2x2 waves over BM rows x 128 cols
  const int bm = blockIdx.y * BM, bn = blockIdx.x * 128;

  f32x4 acc[MI][4] = {};

  auto stage = [&](int buf, int k0) {
#pragma unroll
    for (int i = 0; i < BM / 32; ++i) {  // A: BM x 64 elems
      int idx = i * 2048 + t * 8;
      int row = idx >> 6, col = idx & 63;
      gload_lds16(A + (size_t)(bm + row) * K + (k0 + col), (void*)(&As[buf][0] + i * 2048 + w * 512));
    }
#pragma unroll
    for (int i = 0; i < 4; ++i) {        // B: 128 x 64 elems
      int idx = i * 2048 + t * 8;
      int row = idx >> 6, col = idx & 63;
      gload_lds16(Bw + (size_t)(bn + row) * K + (k0 + col), (void*)(&Bs[buf][0] + i * 2048 + w * 512));
    }
  };

  const int nt = K >> 6;
  stage(0, 0);
  asm volatile("s_waitcnt vmcnt(0)" ::: "memory");
  __syncthreads();
  for (int kt = 0; kt < nt; ++kt) {
    const int cur = kt & 1;
    if (kt + 1 < nt) stage(cur ^ 1, (kt + 1) << 6);   // loads fly during compute
#pragma unroll
    for (int kk = 0; kk < 2; ++kk) {
      bf16x8 af[MI], bfr[4];
#pragma unroll
      for (int mi = 0; mi < MI; ++mi)
        af[mi] = *(const bf16x8*)(&As[cur][0] + (wr * (BM / 2) + mi * 16 + (l & 15)) * 64 + kk * 32 + (l >> 4) * 8);
#pragma unroll
      for (int ni = 0; ni < 4; ++ni)
        bfr[ni] = *(const bf16x8*)(&Bs[cur][0] + (wc * 64 + ni * 16 + (l & 15)) * 64 + kk * 32 + (l >> 4) * 8);
#pragma unroll
      for (int mi = 0; mi < MI; ++mi)
#pragma unroll
        for (int ni = 0; ni < 4; ++ni)
          acc[mi][ni] = __builtin_amdgcn_mfma_f32_16x16x32_bf16(af[mi], bfr[ni], acc[mi][ni], 0, 0, 0);
    }
    asm volatile("s_waitcnt vmcnt(0)" ::: "memory");
    __syncthreads();
  }

  const int r0 = (l >> 4) * 4;   // C/D: row=(lane>>4)*4+reg, col=lane&15
  const int cc = l & 15;
#pragma unroll
  for (int mi = 0; mi < MI; ++mi) {
#pragma unroll
    for (int ni = 0; ni < 4; ++ni) {
      int col = bn + wc * 64 + ni * 16 + cc;
      float bv = bias[col];
#pragma unroll
      for (int r = 0; r < 4; ++r) {
        int row = bm + wr * (BM / 2) + mi * 16 + r0 + r;
        float v = acc[mi][ni][r] + bv;
        if (EPI == 1)
          v = 0.5f * v * (1.f + erff(v * 0.70710678118654752f));   // exact GELU
        Cb[(size_t)row * N + col] = (bf16_t)v;
      }
    }
  }
}

// ---------------- fused attention + out-projection + residual + LN1 ----------------
// grid 512 (XCD-swizzled: batch = bid&7), block = 16 rows. Wave w: rows bm+w*4..+3 serial.
__global__ __launch_bounds__(256) void k_attn_oproj(
    const bf16_t* __restrict__ qkvb,
    const int* __restrict__ nbcol, const float* __restrict__ nbval,
    const int* __restrict__ nbcnt,
    const bf16_t* __restrict__ Wo, const float* __restrict__ bo,
    const bf16_t* __restrict__ residb,
    const float* __restrict__ lnw, const float* __restrict__ lnb,
    bf16_t* __restrict__ xbout) {
  __shared__ __align__(16) char smem[57856];
  bf16_t* Bs    = (bf16_t*)smem;             // [256][64] single-buffer k-tile (32 KB)
  bf16_t* ao    = (bf16_t*)(smem + 32768);   // [16][264] attn out (stride 264 -> 2-way-free frags)
  float*  s_s   = (float*)(smem + 41216);    // [4][8][97] scores
  int*    s_col = (int*)(smem + 53632);      // [4][96]
  float*  s_bia = (float*)(smem + 55168);    // [4][96]
  float*  E     = (float*)(smem + 41216);    // [16][258] f32, aliases attn buffers (dead)
  const int t = threadIdx.x, l = t & 63, w = t >> 6;
  const int b = blockIdx.x & 7;              // XCD-swizzle: one batch per XCD
  const int bm = (b << 10) + (blockIdx.x >> 3) * 16;

  auto stageB = [&](int k0) {
#pragma unroll
    for (int i = 0; i < 8; ++i) {
      int rr = (w * 8 + i) * 8 + (l >> 3), col = (l & 7) * 8;
      gload_lds16(Wo + (size_t)rr * 256 + (k0 + col), (void*)(Bs + (w * 8 + i) * 512));
    }
  };
  stageB(0);   // W_o tile 0 flies during the whole attention phase

  const float scale = 0.17677669529663687f;   // 1/sqrt(32)
  const int h1 = l & 7;
  for (int rr = 0; rr < 4; ++rr) {
    const int row = bm + w * 4 + rr;
    const int deg = nbcnt[row];
    asm volatile("s_waitcnt lgkmcnt(0)" ::: "memory");
    for (int j = l; j < deg; j += 64) {
      s_col[w * 96 + j] = nbcol[(size_t)row * CAP + j];
      s_bia[w * 96 + j] = nbval[(size_t)row * CAP + j];
    }
    float q[32];
    {
      const bf16x8* qp = (const bf16x8*)(qkvb + (size_t)row * 768 + h1 * 32);
#pragma unroll
      for (int u = 0; u < 4; ++u) {
        bf16x8 t8 = qp[u];
#pragma unroll
        for (int j = 0; j < 8; ++j) q[u * 8 + j] = (float)t8[j];
      }
    }
    asm volatile("s_waitcnt lgkmcnt(0)" ::: "memory");

    const int nit = (deg + 7) >> 3;
    float mx = -INFINITY;
    for (int it = 0; it < nit; ++it) {
      int idx = it * 8 + (l >> 3);
      float sc = -INFINITY;
      if (idx < deg) {
        int col = s_col[w * 96 + idx];
        const bf16x8* kr = (const bf16x8*)(qkvb + ((size_t)((b << 10) + col)) * 768 + 256 + h1 * 32);
        float d = 0.f;
#pragma unroll
        for (int u = 0; u < 4; ++u) {
          bf16x8 kv = kr[u];
#pragma unroll
          for (int j = 0; j < 8; ++j) d += (float)kv[j] * q[u * 8 + j];
        }
        sc = d * scale + s_bia[w * 96 + idx];
        s_s[(w * 8 + h1) * 97 + idx] = sc;
      }
      mx = fmaxf(mx, sc);
    }
#pragma unroll
    for (int o = 8; o < 64; o <<= 1) mx = fmaxf(mx, __shfl_xor(mx, o));
    asm volatile("s_waitcnt lgkmcnt(0)" ::: "memory");
    float lsum = 0.f;
    for (int it = 0; it < nit; ++it) {
      int idx = it * 8 + (l >> 3);
      if (idx < deg) {
        float p = __expf(s_s[(w * 8 + h1) * 97 + idx] - mx);
        s_s[(w * 8 + h1) * 97 + idx] = p;
        lsum += p;
      }
    }
#pragma unroll
    for (int o = 8; o < 64; o <<= 1) lsum += __shfl_xor(lsum, o);
    const int h3 = l >> 3;
    float den = __shfl(lsum, h3);
    asm volatile("s_waitcnt lgkmcnt(0)" ::: "memory");
    float a0 = 0.f, a1 = 0.f, a2 = 0.f, a3 = 0.f;
    const bf16_t* vbase = qkvb + ((size_t)(b << 10)) * 768 + 512 + l * 4;
#pragma unroll 4
    for (int idx = 0; idx < deg; ++idx) {
      float p = s_s[(w * 8 + h3) * 97 + idx];
      bf16x4 vv = *(const bf16x4*)(vbase + (size_t)s_col[w * 96 + idx] * 768);
      a0 += p * (float)vv[0]; a1 += p * (float)vv[1];
      a2 += p * (float)vv[2]; a3 += p * (float)vv[3];
    }
    float rden = 1.f / den;
    bf16x4 o4;
    o4[0] = (bf16_t)(a0 * rden); o4[1] = (bf16_t)(a1 * rden);
    o4[2] = (bf16_t)(a2 * rden); o4[3] = (bf16_t)(a3 * rden);
    *(bf16x4*)(ao + (w * 4 + rr) * 264 + l * 4) = o4;
  }
  asm volatile("s_waitcnt vmcnt(0) lgkmcnt(0)" ::: "memory");
  __syncthreads();

  // out-projection: C[16][256] = ao @ Wo^T, K=256 in 4 tiles
  f32x4 acc[4] = {};
  for (int kt = 0; kt < 4; ++kt) {
#pragma unroll
    for (int kk = 0; kk < 2; ++kk) {
      bf16x8 af = *(const bf16x8*)(ao + (l & 15) * 264 + kt * 64 + kk * 32 + (l >> 4) * 8);
#pragma unroll
      for (int ni = 0; ni < 4; ++ni) {
        bf16x8 bfr = *(const bf16x8*)(Bs + (w * 64 + ni * 16 + (l & 15)) * 64 + kk * 32 + (l >> 4) * 8);
        acc[ni] = __builtin_amdgcn_mfma_f32_16x16x32_bf16(af, bfr, acc[ni], 0, 0, 0);
      }
    }
    __syncthreads();
    if (kt < 3) {
      stageB((kt + 1) * 64);
      asm volatile("s_waitcnt vmcnt(0)" ::: "memory");
      __syncthreads();
    }
  }

  const int r0 = (l >> 4) * 4;
  const int cc = l & 15;
#pragma unroll
  for (int ni = 0; ni < 4; ++ni) {
    int col = w * 64 + ni * 16 + cc;
    float bv = bo[col];
#pragma unroll
    for (int r = 0; r < 4; ++r)
      E[(r0 + r) * 258 + col] = acc[ni][r] + bv;
  }
  __syncthreads();

  const int row = t >> 4;
  const int sub = t & 15;
  const float* ep = E + row * 258 + sub * 16;
  const bf16_t* rp = residb + (size_t)(bm + row) * 256 + sub * 16;
  float v[16];
  float s = 0.f;
#pragma unroll
  for (int j = 0; j < 4; ++j) {
    float4 a4 = ((const float4*)ep)[j];
    bf16x4 r4 = ((const bf16x4*)rp)[j];
    v[j * 4 + 0] = a4.x + (float)r4[0]; v[j * 4 + 1] = a4.y + (float)r4[1];
    v[j * 4 + 2] = a4.z + (float)r4[2]; v[j * 4 + 3] = a4.w + (float)r4[3];
    s += v[j * 4 + 0] + v[j * 4 + 1] + v[j * 4 + 2] + v[j * 4 + 3];
  }
#pragma unroll
  for (int o = 1; o < 16; o <<= 1) s += __shfl_xor(s, o);
  float mu = s * (1.f / 256.f);
  float e2 = 0.f;
#pragma unroll
  for (int j = 0; j < 16; ++j) { float d = v[j] - mu; e2 += d * d; }
#pragma unroll
  for (int o = 1; o < 16; o <<= 1) e2 += __shfl_xor(e2, o);
  float rs = rsqrtf(e2 * (1.f / 256.f) + 1e-5f);
  bf16_t* xbo = xbout + (size_t)(bm + row) * 256 + sub * 16;
#pragma unroll
  for (int j = 0; j < 4; ++j) {
    float4 w4 = ((const float4*)(lnw + sub * 16))[j];
    float4 b4 = ((const float4*)(lnb + sub * 16))[j];
    bf16x4 ob;
    ob[0] = (bf16_t)((v[j * 4 + 0] - mu) * rs * w4.x + b4.x);
    ob[1] = (bf16_t)((v[j * 4 + 1] - mu) * rs * w4.y + b4.y);
    ob[2] = (bf16_t)((v[j * 4 + 2] - mu) * rs * w4.z + b4.z);
    ob[3] = (bf16_t)((v[j * 4 + 3] - mu) * rs * w4.w + b4.w);
    ((bf16x4*)xbo)[j] = ob;
  }
}

// ---------------- fused GEMM(BM=16, BN=256) + bias + bf16-residual + LayerNorm ----------------
// race-free pipeline. FIN=0: bf16 xbout. FIN=1: additionally lnf(y) -> f32 outf (d_out).
template <int FIN>
__global__ __launch_bounds__(256) void gemm_ln(
    const bf16_t* __restrict__ A, const bf16_t* __restrict__ Bw,
    const float* __restrict__ bias, const bf16_t* __restrict__ residb,
    const float* __restrict__ lnw, const float* __restrict__ lnb,
    const float* __restrict__ lnfw, const float* __restrict__ lnfb,
    bf16_t* __restrict__ xbout, float* __restrict__ outf, int K) {
  __shared__ __align__(16) char smem[69632];
  bf16_t* As = (bf16_t*)smem;             // [2][16][64] = 4KB
  bf16_t* Bs = (bf16_t*)(smem + 4096);    // [2][256][64] = 64KB
  float*  E  = (float*)smem;              // epi: [16][258] f32 (aliases, after barrier)
  const int t = threadIdx.x;
  const int l = t & 63;
  const int w = t >> 6;
  const int bm = blockIdx.x * 16;

  f32x4 acc[4] = {};

  auto stage = [&](int buf, int k0) {
    if (w < 2) {
      int row = w * 8 + (l >> 3), col = (l & 7) * 8;
      gload_lds16(A + (size_t)(bm + row) * K + (k0 + col), (void*)(As + buf * 1024 + w * 512));
    }
#pragma unroll
    for (int i = 0; i < 8; ++i) {
      int rr = (w * 8 + i) * 8 + (l >> 3), col = (l & 7) * 8;
      gload_lds16(Bw + (size_t)rr * K + (k0 + col), (void*)(Bs + buf * 16384 + (w * 8 + i) * 512));
    }
  };

  const int nt = K >> 6;
  stage(0, 0);
  asm volatile("s_waitcnt vmcnt(0)" ::: "memory");
  __syncthreads();
  for (int kt = 0; kt < nt; ++kt) {
    const int cur = kt & 1;
    if (kt + 1 < nt) stage(cur ^ 1, (kt + 1) << 6);
#pragma unroll
    for (int kk = 0; kk < 2; ++kk) {
      bf16x8 af = *(const bf16x8*)(As + cur * 1024 + (l & 15) * 64 + kk * 32 + (l >> 4) * 8);
#pragma unroll
      for (int ni = 0; ni < 4; ++ni) {
        bf16x8 bfr = *(const bf16x8*)(Bs + cur * 16384 + (w * 64 + ni * 16 + (l & 15)) * 64 + kk * 32 + (l >> 4) * 8);
        acc[ni] = __builtin_amdgcn_mfma_f32_16x16x32_bf16(af, bfr, acc[ni], 0, 0, 0);
      }
    }
    asm volatile("s_waitcnt vmcnt(0)" ::: "memory");
    __syncthreads();
  }

  const int r0 = (l >> 4) * 4;
  const int cc = l & 15;
#pragma unroll
  for (int ni = 0; ni < 4; ++ni) {
    int col = w * 64 + ni * 16 + cc;
    float bv = bias[col];
#pragma unroll
    for (int r = 0; r < 4; ++r)
      E[(r0 + r) * 258 + col] = acc[ni][r] + bv;
  }
  __syncthreads();

  const int row = t >> 4;
  const int sub = t & 15;
  const float* ep = E + row * 258 + sub * 16;
  const bf16_t* rp = residb + (size_t)(bm + row) * 256 + sub * 16;
  float v[16];
  float s = 0.f;
#pragma unroll
  for (int j = 0; j < 4; ++j) {
    float4 a4 = ((const float4*)ep)[j];
    bf16x4 r4 = ((const bf16x4*)rp)[j];
    v[j * 4 + 0] = a4.x + (float)r4[0]; v[j * 4 + 1] = a4.y + (float)r4[1];
    v[j * 4 + 2] = a4.z + (float)r4[2]; v[j * 4 + 3] = a4.w + (float)r4[3];
    s += v[j * 4 + 0] + v[j * 4 + 1] + v[j * 4 + 2] + v[j * 4 + 3];
  }
#pragma unroll
  for (int o = 1; o < 16; o <<= 1) s += __shfl_xor(s, o);
  float mu = s * (1.f / 256.f);
  float e2 = 0.f;
#pragma unroll
  for (int j = 0; j < 16; ++j) { float d = v[j] - mu; e2 += d * d; }
#pragma unroll
  for (int o = 1; o < 16; o <<= 1) e2 += __shfl_xor(e2, o);
  float rs = rsqrtf(e2 * (1.f / 256.f) + 1e-5f);
  float y[16];
#pragma unroll
  for (int j = 0; j < 4; ++j) {
    float4 w4 = ((const float4*)(lnw + sub * 16))[j];
    float4 b4 = ((const float4*)(lnb + sub * 16))[j];
    y[j * 4 + 0] = (v[j * 4 + 0] - mu) * rs * w4.x + b4.x;
    y[j * 4 + 1] = (v[j * 4 + 1] - mu) * rs * w4.y + b4.y;
    y[j * 4 + 2] = (v[j * 4 + 2] - mu) * rs * w4.z + b4.z;
    y[j * 4 + 3] = (v[j * 4 + 3] - mu) * rs * w4.w + b4.w;
  }
  if (FIN == 0) {
    bf16_t* xbo = xbout + (size_t)(bm + row) * 256 + sub * 16;
#pragma unroll
    for (int j = 0; j < 4; ++j) {
      bf16x4 ob;
      ob[0] = (bf16_t)y[j * 4 + 0]; ob[1] = (bf16_t)y[j * 4 + 1];
      ob[2] = (bf16_t)y[j * 4 + 2]; ob[3] = (bf16_t)y[j * 4 + 3];
      ((bf16x4*)xbo)[j] = ob;
    }
  } else {
    float s2 = 0.f;
#pragma unroll
    for (int j = 0; j < 16; ++j) s2 += y[j];
#pragma unroll
    for (int o = 1; o < 16; o <<= 1) s2 += __shfl_xor(s2, o);
    float mu2 = s2 * (1.f / 256.f);
    float q2 = 0.f;
#pragma unroll
    for (int j = 0; j < 16; ++j) { float d = y[j] - mu2; q2 += d * d; }
#pragma unroll
    for (int o = 1; o < 16; o <<= 1) q2 += __shfl_xor(q2, o);
    float rs2 = rsqrtf(q2 * (1.f / 256.f) + 1e-5f);
    float* xo = outf + (size_t)(bm + row) * 256 + sub * 16;
#pragma unroll
    for (int j = 0; j < 4; ++j) {
      float4 w4 = ((const float4*)(lnfw + sub * 16))[j];
      float4 b4 = ((const float4*)(lnfb + sub * 16))[j];
      float4 o4 = {(y[j * 4 + 0] - mu2) * rs2 * w4.x + b4.x,
                   (y[j * 4 + 1] - mu2) * rs2 * w4.y + b4.y,
                   (y[j * 4 + 2] - mu2) * rs2 * w4.z + b4.z,
                   (y[j * 4 + 3] - mu2) * rs2 * w4.w + b4.w};
      ((float4*)xo)[j] = o4;
    }
  }
}

extern "C" void kernel_launch(void* const* d_in, const int* in_sizes, int n_in,
                              void* d_out, int out_size, void* d_ws, size_t ws_size,
                              hipStream_t stream) {
  const float* H    = (const float*)d_in[0];
  const int*   ei   = (const int*)d_in[1];
  const float* m    = (const float*)d_in[2];
  const float* Wqkv = (const float*)d_in[3];
  const float* bqkv = (const float*)d_in[4];
  const float* Wo   = (const float*)d_in[5];
  const float* bo   = (const float*)d_in[6];
  const float* ln1w = (const float*)d_in[7];
  const float* ln1b = (const float*)d_in[8];
  const float* W1   = (const float*)d_in[9];
  const float* b1   = (const float*)d_in[10];
  const float* W2   = (const float*)d_in[11];
  const float* b2   = (const float*)d_in[12];
  const float* ln2w = (const float*)d_in[13];
  const float* ln2b = (const float*)d_in[14];
  const float* lnfw = (const float*)d_in[15];
  const float* lnfb = (const float*)d_in[16];

  char* ws = (char*)d_ws;
  size_t off = 0;
  auto alloc = [&](size_t bytes) {
    void* p = ws + off;
    off += (bytes + 255) & ~(size_t)255;
    return p;
  };

  int*    cnt   = (int*)alloc((size_t)BATCH * NTOK * 4);
  int*    ent   = (int*)alloc((size_t)BATCH * NTOK * CAP * 4);
  int*    nbcol = (int*)alloc((size_t)BATCH * NTOK * CAP * 4);
  float*  nbval = (float*)alloc((size_t)BATCH * NTOK * CAP * 4);
  int*    nbcnt = (int*)alloc((size_t)BATCH * NTOK * 4);
  bf16_t* qkvb  = (bf16_t*)alloc((size_t)8192 * 768 * 2);
  bf16_t* wqkvb = (bf16_t*)alloc((size_t)2 * 768 * 256 * 2);
  bf16_t* wob   = (bf16_t*)alloc((size_t)2 * 256 * 256 * 2);
  bf16_t* w1b   = (bf16_t*)alloc((size_t)2 * 1024 * 256 * 2);
  bf16_t* w2b   = (bf16_t*)alloc((size_t)2 * 256 * 1024 * 2);
  bf16_t* xb    = (bf16_t*)alloc((size_t)8192 * 256 * 2);   // layer input x (bf16)
  bf16_t* x1b   = (bf16_t*)alloc((size_t)8192 * 256 * 2);   // after ln1
  bf16_t* ffb   = (bf16_t*)alloc((size_t)8192 * 1024 * 2);

  k_pre<<<3584, 256, 0, stream>>>((int4*)cnt, H, Wqkv, Wo, W1, W2,
                                  xb, wqkvb, wob, w1b, w2b);
  k_scatter2<<<(BATCH * NEDGE + 255) / 256, 256, 0, stream>>>(ei, cnt, ent);
  k_build2<<<BATCH * NTOK / 4, 256, 0, stream>>>(cnt, ent, m, nbcol, nbval, nbcnt);

  for (int lyr = 0; lyr < 2; ++lyr) {
    gemm_bt<3, 64><<<dim3(768 / 128, 8192 / 64), 256, 0, stream>>>(
        xb, wqkvb + (size_t)lyr * 768 * 256, bqkv + lyr * 768, qkvb, 8192, 768, 256);
    k_attn_oproj<<<512, 256, 0, stream>>>(
        qkvb, nbcol, nbval, nbcnt,
        wob + (size_t)lyr * 256 * 256, bo + lyr * 256, xb,
        ln1w + lyr * 256, ln1b + lyr * 256, x1b);
    gemm_bt<1, 128><<<dim3(1024 / 128, 8192 / 128), 256, 0, stream>>>(
        x1b, w1b + (size_t)lyr * 1024 * 256, b1 + lyr * 1024, ffb, 8192, 1024, 256);
    if (lyr == 0) {
      gemm_ln<0><<<512, 256, 0, stream>>>(
          ffb, w2b + (size_t)lyr * 256 * 1024, b2 + lyr * 256, x1b,
          ln2w + lyr * 256, ln2b + lyr * 256, nullptr, nullptr, xb, nullptr, 1024);
    } else {
      gemm_ln<1><<<512, 256, 0, stream>>>(
          ffb, w2b + (size_t)lyr * 256 * 1024, b2 + lyr * 256, x1b,
          ln2w + lyr * 256, ln2b + lyr * 256, lnfw, lnfb, nullptr, (float*)d_out, 1024);
    }
  }
}

// Round 14
// 192.068 us; speedup vs baseline: 1.2078x; 1.0170x over previous
//
#include <hip/hip_runtime.h>
#include <hip/hip_bf16.h>
#include <math.h>

typedef __bf16 bf16_t;
typedef __attribute__((ext_vector_type(8))) __bf16 bf16x8;
typedef __attribute__((ext_vector_type(4))) __bf16 bf16x4;
typedef __attribute__((ext_vector_type(4))) float f32x4;

#define BATCH 8
#define NTOK 1024
#define NEDGE 16384
#define CAP 96   // max entries per row (deg ~ Poisson(32); P(deg>96) < 1e-20)

// ---------------- async global->LDS (16B per lane, wave-uniform LDS base) ----------------
__device__ __forceinline__ void gload_lds16(const void* g, void* l) {
  __builtin_amdgcn_global_load_lds(
      (const __attribute__((address_space(1))) unsigned int*)(uintptr_t)g,
      (__attribute__((address_space(3))) unsigned int*)(unsigned int)(uintptr_t)l,
      16, 0, 0);
}

// ---------------- fused: f32->bf16 cvt for H + weights; blocks <8 also zero cnt ----------------
__global__ void k_pre(int4* __restrict__ cnt,
                      const float* __restrict__ H, const float* __restrict__ Wqkv,
                      const float* __restrict__ Wo, const float* __restrict__ W1,
                      const float* __restrict__ W2, bf16_t* __restrict__ xb,
                      bf16_t* __restrict__ wqkvb, bf16_t* __restrict__ wob,
                      bf16_t* __restrict__ w1b, bf16_t* __restrict__ w2b) {
  int i = blockIdx.x * 256 + threadIdx.x;   // float4-quad index
  if (blockIdx.x < 8) {
    int4 z = {0, 0, 0, 0};
    cnt[i] = z;                             // 8 blocks x 256 x int4 = 8192 ints
  }
  const float* s; bf16_t* d; int off;
  if (i < 524288)      { s = H;    d = xb;    off = i; }
  else if (i < 622592) { s = Wqkv; d = wqkvb; off = i - 524288; }
  else if (i < 655360) { s = Wo;   d = wob;   off = i - 622592; }
  else if (i < 786432) { s = W1;   d = w1b;   off = i - 655360; }
  else if (i < 917504) { s = W2;   d = w2b;   off = i - 786432; }
  else return;
  float4 v = ((const float4*)s)[off];
  bf16x4 o;
  o[0] = (bf16_t)v.x; o[1] = (bf16_t)v.y; o[2] = (bf16_t)v.z; o[3] = (bf16_t)v.w;
  ((bf16x4*)d)[off] = o;
}

// ---------------- edge scatter: packed (prio<<10|col) appended to per-row lists ----------------
__global__ void k_scatter2(const int* __restrict__ ei, int* __restrict__ cnt,
                           int* __restrict__ ent) {
  int idx = blockIdx.x * 256 + threadIdx.x;
  if (idx >= BATCH * NEDGE) return;
  int b = idx >> 14;
  int e = idx & (NEDGE - 1);
  const int* eb = ei + (size_t)b * 2 * NEDGE;
  int r = eb[e], c = eb[NEDGE + e];
  int rowr = (b << 10) + r, rowc = (b << 10) + c;
  int q = atomicAdd(cnt + rowr, 1);
  if (q < CAP) ent[rowr * CAP + q] = ((e + 1) << 10) | c;
  q = atomicAdd(cnt + rowc, 1);
  if (q < CAP) ent[rowc * CAP + q] = ((NEDGE + e + 1) << 10) | r;
}

// ---------------- CSR build v2: dedup per row in LDS, canonical ascending-col order ----------------
__global__ __launch_bounds__(256) void k_build2(
    const int* __restrict__ cnt, const int* __restrict__ ent,
    const float* __restrict__ mptr,
    int* __restrict__ nbcol, float* __restrict__ nbval, int* __restrict__ nbcnt) {
  const int w = threadIdx.x >> 6;
  const int l = threadIdx.x & 63;
  const int row = blockIdx.x * 4 + w;   // b*1024 + i
  const int i = row & 1023;
  const int b = row >> 10;
  __shared__ int sE[4][CAP];
  __shared__ int sW[4][CAP];
  const int n = min(cnt[row], CAP);
  for (int j = l; j < n; j += 64) sE[w][j] = ent[(size_t)row * CAP + j];
  __syncthreads();

  bool dcov_l = false;
  bool win[2] = {false, false};
  int myc[2], myp[2];
#pragma unroll
  for (int s = 0; s < 2; ++s) {
    int k = s * 64 + l;
    if (k < n) {
      int pk = sE[w][k], ck = pk & 1023;
      myc[s] = ck; myp[s] = pk;
      bool wn = true;
      for (int j = 0; j < n; ++j) {
        int pj = sE[w][j];
        if ((pj & 1023) == ck && pj > pk) wn = false;
      }
      win[s] = wn;
      sW[w][k] = wn ? 1 : 0;
      if (ck == i) dcov_l = true;
    }
  }
  const bool dcov = __any(dcov_l);
  unsigned long long m0 = __ballot(win[0]);
  unsigned long long m1 = __ballot(win[1]);
  if (l == 0) nbcnt[row] = __popcll(m0) + __popcll(m1) + (dcov ? 0 : 1);

#pragma unroll
  for (int s = 0; s < 2; ++s) {
    int k = s * 64 + l;
    if (k < n && win[s]) {
      int pos = 0;
      for (int j = 0; j < n; ++j)
        if (sW[w][j] && (sE[w][j] & 1023) < myc[s]) ++pos;
      if (!dcov && i < myc[s]) ++pos;
      int e = ((myp[s] >> 10) - 1) & (NEDGE - 1);
      float v = logf(mptr[(size_t)b * NEDGE + e] + 1e-9f);
      if (pos < CAP) {
        nbcol[(size_t)row * CAP + pos] = myc[s];
        nbval[(size_t)row * CAP + pos] = v;
      }
    }
  }
  if (!dcov && l == 0) {   // virtual diagonal (value 0)
    int pos = 0;
    for (int j = 0; j < n; ++j)
      if (sW[w][j] && (sE[w][j] & 1023) < i) ++pos;
    nbcol[(size_t)row * CAP + pos] = i;
    nbval[(size_t)row * CAP + pos] = 0.f;
  }
}

// ---------------- GEMM BMx128 tile, dbuf LDS, race-free single-barrier pipeline ----------------
// 1-D grid + XCD-contiguous swizzle: XCD c gets tiles [c*nwg/8, (c+1)*nwg/8) in row-major
// order -> per-XCD A-slab (~0.5MB) + full B (~0.5MB) stay L2-resident, fetched once.
// loop: stage(t+1, buf^1) -> compute(t, buf) -> vmcnt(0) -> barrier.
// EPI 1: gelu -> bf16 out. EPI 3: plain bf16 out.  BM in {64,128}.
template <int EPI, int BM>
__global__ __launch_bounds__(256) void gemm_bt(
    const bf16_t* __restrict__ A, const bf16_t* __restrict__ Bw,
    const float* __restrict__ bias, bf16_t* __restrict__ Cb,
    int M, int N, int K) {
  constexpr int MI = BM / 32;            // acc rows per wave
  __shared__ bf16_t As[2][BM * 64];
  __shared__ bf16_t Bs[2][128 * 64];
  const int t = threadIdx.x;
  const int l = t & 63;
  const int w = t >> 6;
  const int wr = w >> 1, wc = w & 1;     // 2x2 waves over BM rows x 128 cols
  // XCD swizzle (nwg % 8 == 0 guaranteed by launch): round-robin bid -> contiguous per-XCD range
  const int per = gridDim.x >> 3;
  const int g2 = (blockIdx.x & 7) * per + (blockIdx.x >> 3);
  const int NX = N >> 7;                 // N/128 column tiles
  const int bm = (g2 / NX) * BM, bn = (g2 % NX) * 128;

  f32x4 acc[MI][4] = {};

  auto stage = [&](int buf, int k0) {
#pragma unroll
    for (int i = 0; i < BM / 32; ++i) {  // A: BM x 64 elems
      int idx = i * 2048 + t * 8;
      int row = idx >> 6, col = idx & 63;
      gload_lds16(A + (size_t)(bm + row) * K + (k0 + col), (void*)(&As[buf][0] + i * 2048 + w * 512));
    }
#pragma unroll
    for (int i = 0; i < 4; ++i) {        // B: 128 x 64 elems
      int idx = i * 2048 + t * 8;
      int row = idx >> 6, col = idx & 63;
      gload_lds16(Bw + (size_t)(bn + row) * K + (k0 + col), (void*)(&Bs[buf][0] + i * 2048 + w * 512));
    }
  };

  const int nt = K >> 6;
  stage(0, 0);
  asm volatile("s_waitcnt vmcnt(0)" ::: "memory");
  __syncthreads();
  for (int kt = 0; kt < nt; ++kt) {
    const int cur = kt & 1;
    if (kt + 1 < nt) stage(cur ^ 1, (kt + 1) << 6);   // loads fly during compute
#pragma unroll
    for (int kk = 0; kk < 2; ++kk) {
      bf16x8 af[MI], bfr[4];
#pragma unroll
      for (int mi = 0; mi < MI; ++mi)
        af[mi] = *(const bf16x8*)(&As[cur][0] + (wr * (BM / 2) + mi * 16 + (l & 15)) * 64 + kk * 32 + (l >> 4) * 8);
#pragma unroll
      for (int ni = 0; ni < 4; ++ni)
        bfr[ni] = *(const bf16x8*)(&Bs[cur][0] + (wc * 64 + ni * 16 + (l & 15)) * 64 + kk * 32 + (l >> 4) * 8);
#pragma unroll
      for (int mi = 0; mi < MI; ++mi)
#pragma unroll
        for (int ni = 0; ni < 4; ++ni)
          acc[mi][ni] = __builtin_amdgcn_mfma_f32_16x16x32_bf16(af[mi], bfr[ni], acc[mi][ni], 0, 0, 0);
    }
    asm volatile("s_waitcnt vmcnt(0)" ::: "memory");
    __syncthreads();
  }

  const int r0 = (l >> 4) * 4;   // C/D: row=(lane>>4)*4+reg, col=lane&15
  const int cc = l & 15;
#pragma unroll
  for (int mi = 0; mi < MI; ++mi) {
#pragma unroll
    for (int ni = 0; ni < 4; ++ni) {
      int col = bn + wc * 64 + ni * 16 + cc;
      float bv = bias[col];
#pragma unroll
      for (int r = 0; r < 4; ++r) {
        int row = bm + wr * (BM / 2) + mi * 16 + r0 + r;
        float v = acc[mi][ni][r] + bv;
        if (EPI == 1)
          v = 0.5f * v * (1.f + erff(v * 0.70710678118654752f));   // exact GELU
        Cb[(size_t)row * N + col] = (bf16_t)v;
      }
    }
  }
}

// ---------------- fused attention + out-projection + residual + LN1 ----------------
// grid 512 (XCD-swizzled: batch = bid&7), block = 16 rows. Wave w: rows bm+w*4..+3 serial.
__global__ __launch_bounds__(256) void k_attn_oproj(
    const bf16_t* __restrict__ qkvb,
    const int* __restrict__ nbcol, const float* __restrict__ nbval,
    const int* __restrict__ nbcnt,
    const bf16_t* __restrict__ Wo, const float* __restrict__ bo,
    const bf16_t* __restrict__ residb,
    const float* __restrict__ lnw, const float* __restrict__ lnb,
    bf16_t* __restrict__ xbout) {
  __shared__ __align__(16) char smem[57856];
  bf16_t* Bs    = (bf16_t*)smem;             // [256][64] single-buffer k-tile (32 KB)
  bf16_t* ao    = (bf16_t*)(smem + 32768);   // [16][264] attn out (stride 264 -> 2-way-free frags)
  float*  s_s   = (float*)(smem + 41216);    // [4][8][97] scores
  int*    s_col = (int*)(smem + 53632);      // [4][96]
  float*  s_bia = (float*)(smem + 55168);    // [4][96]
  float*  E     = (float*)(smem + 41216);    // [16][258] f32, aliases attn buffers (dead)
  const int t = threadIdx.x, l = t & 63, w = t >> 6;
  const int b = blockIdx.x & 7;              // XCD-swizzle: one batch per XCD
  const int bm = (b << 10) + (blockIdx.x >> 3) * 16;

  auto stageB = [&](int k0) {
#pragma unroll
    for (int i = 0; i < 8; ++i) {
      int rr = (w * 8 + i) * 8 + (l >> 3), col = (l & 7) * 8;
      gload_lds16(Wo + (size_t)rr * 256 + (k0 + col), (void*)(Bs + (w * 8 + i) * 512));
    }
  };
  stageB(0);   // W_o tile 0 flies during the whole attention phase

  const float scale = 0.17677669529663687f;   // 1/sqrt(32)
  const int h1 = l & 7;
  for (int rr = 0; rr < 4; ++rr) {
    const int row = bm + w * 4 + rr;
    const int deg = nbcnt[row];
    asm volatile("s_waitcnt lgkmcnt(0)" ::: "memory");
    for (int j = l; j < deg; j += 64) {
      s_col[w * 96 + j] = nbcol[(size_t)row * CAP + j];
      s_bia[w * 96 + j] = nbval[(size_t)row * CAP + j];
    }
    float q[32];
    {
      const bf16x8* qp = (const bf16x8*)(qkvb + (size_t)row * 768 + h1 * 32);
#pragma unroll
      for (int u = 0; u < 4; ++u) {
        bf16x8 t8 = qp[u];
#pragma unroll
        for (int j = 0; j < 8; ++j) q[u * 8 + j] = (float)t8[j];
      }
    }
    asm volatile("s_waitcnt lgkmcnt(0)" ::: "memory");

    const int nit = (deg + 7) >> 3;
    float mx = -INFINITY;
    for (int it = 0; it < nit; ++it) {
      int idx = it * 8 + (l >> 3);
      float sc = -INFINITY;
      if (idx < deg) {
        int col = s_col[w * 96 + idx];
        const bf16x8* kr = (const bf16x8*)(qkvb + ((size_t)((b << 10) + col)) * 768 + 256 + h1 * 32);
        float d = 0.f;
#pragma unroll
        for (int u = 0; u < 4; ++u) {
          bf16x8 kv = kr[u];
#pragma unroll
          for (int j = 0; j < 8; ++j) d += (float)kv[j] * q[u * 8 + j];
        }
        sc = d * scale + s_bia[w * 96 + idx];
        s_s[(w * 8 + h1) * 97 + idx] = sc;
      }
      mx = fmaxf(mx, sc);
    }
#pragma unroll
    for (int o = 8; o < 64; o <<= 1) mx = fmaxf(mx, __shfl_xor(mx, o));
    asm volatile("s_waitcnt lgkmcnt(0)" ::: "memory");
    float lsum = 0.f;
    for (int it = 0; it < nit; ++it) {
      int idx = it * 8 + (l >> 3);
      if (idx < deg) {
        float p = __expf(s_s[(w * 8 + h1) * 97 + idx] - mx);
        s_s[(w * 8 + h1) * 97 + idx] = p;
        lsum += p;
      }
    }
#pragma unroll
    for (int o = 8; o < 64; o <<= 1) lsum += __shfl_xor(lsum, o);
    const int h3 = l >> 3;
    float den = __shfl(lsum, h3);
    asm volatile("s_waitcnt lgkmcnt(0)" ::: "memory");
    float a0 = 0.f, a1 = 0.f, a2 = 0.f, a3 = 0.f;
    const bf16_t* vbase = qkvb + ((size_t)(b << 10)) * 768 + 512 + l * 4;
#pragma unroll 4
    for (int idx = 0; idx < deg; ++idx) {
      float p = s_s[(w * 8 + h3) * 97 + idx];
      bf16x4 vv = *(const bf16x4*)(vbase + (size_t)s_col[w * 96 + idx] * 768);
      a0 += p * (float)vv[0]; a1 += p * (float)vv[1];
      a2 += p * (float)vv[2]; a3 += p * (float)vv[3];
    }
    float rden = 1.f / den;
    bf16x4 o4;
    o4[0] = (bf16_t)(a0 * rden); o4[1] = (bf16_t)(a1 * rden);
    o4[2] = (bf16_t)(a2 * rden); o4[3] = (bf16_t)(a3 * rden);
    *(bf16x4*)(ao + (w * 4 + rr) * 264 + l * 4) = o4;
  }
  asm volatile("s_waitcnt vmcnt(0) lgkmcnt(0)" ::: "memory");
  __syncthreads();

  // out-projection: C[16][256] = ao @ Wo^T, K=256 in 4 tiles
  f32x4 acc[4] = {};
  for (int kt = 0; kt < 4; ++kt) {
#pragma unroll
    for (int kk = 0; kk < 2; ++kk) {
      bf16x8 af = *(const bf16x8*)(ao + (l & 15) * 264 + kt * 64 + kk * 32 + (l >> 4) * 8);
#pragma unroll
      for (int ni = 0; ni < 4; ++ni) {
        bf16x8 bfr = *(const bf16x8*)(Bs + (w * 64 + ni * 16 + (l & 15)) * 64 + kk * 32 + (l >> 4) * 8);
        acc[ni] = __builtin_amdgcn_mfma_f32_16x16x32_bf16(af, bfr, acc[ni], 0, 0, 0);
      }
    }
    __syncthreads();
    if (kt < 3) {
      stageB((kt + 1) * 64);
      asm volatile("s_waitcnt vmcnt(0)" ::: "memory");
      __syncthreads();
    }
  }

  const int r0 = (l >> 4) * 4;
  const int cc = l & 15;
#pragma unroll
  for (int ni = 0; ni < 4; ++ni) {
    int col = w * 64 + ni * 16 + cc;
    float bv = bo[col];
#pragma unroll
    for (int r = 0; r < 4; ++r)
      E[(r0 + r) * 258 + col] = acc[ni][r] + bv;
  }
  __syncthreads();

  const int row = t >> 4;
  const int sub = t & 15;
  const float* ep = E + row * 258 + sub * 16;
  const bf16_t* rp = residb + (size_t)(bm + row) * 256 + sub * 16;
  float v[16];
  float s = 0.f;
#pragma unroll
  for (int j = 0; j < 4; ++j) {
    float4 a4 = ((const float4*)ep)[j];
    bf16x4 r4 = ((const bf16x4*)rp)[j];
    v[j * 4 + 0] = a4.x + (float)r4[0]; v[j * 4 + 1] = a4.y + (float)r4[1];
    v[j * 4 + 2] = a4.z + (float)r4[2]; v[j * 4 + 3] = a4.w + (float)r4[3];
    s += v[j * 4 + 0] + v[j * 4 + 1] + v[j * 4 + 2] + v[j * 4 + 3];
  }
#pragma unroll
  for (int o = 1; o < 16; o <<= 1) s += __shfl_xor(s, o);
  float mu = s * (1.f / 256.f);
  float e2 = 0.f;
#pragma unroll
  for (int j = 0; j < 16; ++j) { float d = v[j] - mu; e2 += d * d; }
#pragma unroll
  for (int o = 1; o < 16; o <<= 1) e2 += __shfl_xor(e2, o);
  float rs = rsqrtf(e2 * (1.f / 256.f) + 1e-5f);
  bf16_t* xbo = xbout + (size_t)(bm + row) * 256 + sub * 16;
#pragma unroll
  for (int j = 0; j < 4; ++j) {
    float4 w4 = ((const float4*)(lnw + sub * 16))[j];
    float4 b4 = ((const float4*)(lnb + sub * 16))[j];
    bf16x4 ob;
    ob[0] = (bf16_t)((v[j * 4 + 0] - mu) * rs * w4.x + b4.x);
    ob[1] = (bf16_t)((v[j * 4 + 1] - mu) * rs * w4.y + b4.y);
    ob[2] = (bf16_t)((v[j * 4 + 2] - mu) * rs * w4.z + b4.z);
    ob[3] = (bf16_t)((v[j * 4 + 3] - mu) * rs * w4.w + b4.w);
    ((bf16x4*)xbo)[j] = ob;
  }
}

// ---------------- fused GEMM(BM=16, BN=256) + bias + bf16-residual + LayerNorm ----------------
// XCD-contiguous row-tile swizzle; race-free pipeline.
// FIN=0: bf16 xbout. FIN=1: additionally lnf(y) -> f32 outf (d_out).
template <int FIN>
__global__ __launch_bounds__(256) void gemm_ln(
    const bf16_t* __restrict__ A, const bf16_t* __restrict__ Bw,
    const float* __restrict__ bias, const bf16_t* __restrict__ residb,
    const float* __restrict__ lnw, const float* __restrict__ lnb,
    const float* __restrict__ lnfw, const float* __restrict__ lnfb,
    bf16_t* __restrict__ xbout, float* __restrict__ outf, int K) {
  __shared__ __align__(16) char smem[69632];
  bf16_t* As = (bf16_t*)smem;             // [2][16][64] = 4KB
  bf16_t* Bs = (bf16_t*)(smem + 4096);    // [2][256][64] = 64KB
  float*  E  = (float*)smem;              // epi: [16][258] f32 (aliases, after barrier)
  const int t = threadIdx.x;
  const int l = t & 63;
  const int w = t >> 6;
  const int per = gridDim.x >> 3;
  const int g2 = (blockIdx.x & 7) * per + (blockIdx.x >> 3);   // XCD-contiguous rows
  const int bm = g2 * 16;

  f32x4 acc[4] = {};

  auto stage = [&](int buf, int k0) {
    if (w < 2) {
      int row = w * 8 + (l >> 3), col = (l & 7) * 8;
      gload_lds16(A + (size_t)(bm + row) * K + (k0 + col), (void*)(As + buf * 1024 + w * 512));
    }
#pragma unroll
    for (int i = 0; i < 8; ++i) {
      int rr = (w * 8 + i) * 8 + (l >> 3), col = (l & 7) * 8;
      gload_lds16(Bw + (size_t)rr * K + (k0 + col), (void*)(Bs + buf * 16384 + (w * 8 + i) * 512));
    }
  };

  const int nt = K >> 6;
  stage(0, 0);
  asm volatile("s_waitcnt vmcnt(0)" ::: "memory");
  __syncthreads();
  for (int kt = 0; kt < nt; ++kt) {
    const int cur = kt & 1;
    if (kt + 1 < nt) stage(cur ^ 1, (kt + 1) << 6);
#pragma unroll
    for (int kk = 0; kk < 2; ++kk) {
      bf16x8 af = *(const bf16x8*)(As + cur * 1024 + (l & 15) * 64 + kk * 32 + (l >> 4) * 8);
#pragma unroll
      for (int ni = 0; ni < 4; ++ni) {
        bf16x8 bfr = *(const bf16x8*)(Bs + cur * 16384 + (w * 64 + ni * 16 + (l & 15)) * 64 + kk * 32 + (l >> 4) * 8);
        acc[ni] = __builtin_amdgcn_mfma_f32_16x16x32_bf16(af, bfr, acc[ni], 0, 0, 0);
      }
    }
    asm volatile("s_waitcnt vmcnt(0)" ::: "memory");
    __syncthreads();
  }

  const int r0 = (l >> 4) * 4;
  const int cc = l & 15;
#pragma unroll
  for (int ni = 0; ni < 4; ++ni) {
    int col = w * 64 + ni * 16 + cc;
    float bv = bias[col];
#pragma unroll
    for (int r = 0; r < 4; ++r)
      E[(r0 + r) * 258 + col] = acc[ni][r] + bv;
  }
  __syncthreads();

  const int row = t >> 4;
  const int sub = t & 15;
  const float* ep = E + row * 258 + sub * 16;
  const bf16_t* rp = residb + (size_t)(bm + row) * 256 + sub * 16;
  float v[16];
  float s = 0.f;
#pragma unroll
  for (int j = 0; j < 4; ++j) {
    float4 a4 = ((const float4*)ep)[j];
    bf16x4 r4 = ((const bf16x4*)rp)[j];
    v[j * 4 + 0] = a4.x + (float)r4[0]; v[j * 4 + 1] = a4.y + (float)r4[1];
    v[j * 4 + 2] = a4.z + (float)r4[2]; v[j * 4 + 3] = a4.w + (float)r4[3];
    s += v[j * 4 + 0] + v[j * 4 + 1] + v[j * 4 + 2] + v[j * 4 + 3];
  }
#pragma unroll
  for (int o = 1; o < 16; o <<= 1) s += __shfl_xor(s, o);
  float mu = s * (1.f / 256.f);
  float e2 = 0.f;
#pragma unroll
  for (int j = 0; j < 16; ++j) { float d = v[j] - mu; e2 += d * d; }
#pragma unroll
  for (int o = 1; o < 16; o <<= 1) e2 += __shfl_xor(e2, o);
  float rs = rsqrtf(e2 * (1.f / 256.f) + 1e-5f);
  float y[16];
#pragma unroll
  for (int j = 0; j < 4; ++j) {
    float4 w4 = ((const float4*)(lnw + sub * 16))[j];
    float4 b4 = ((const float4*)(lnb + sub * 16))[j];
    y[j * 4 + 0] = (v[j * 4 + 0] - mu) * rs * w4.x + b4.x;
    y[j * 4 + 1] = (v[j * 4 + 1] - mu) * rs * w4.y + b4.y;
    y[j * 4 + 2] = (v[j * 4 + 2] - mu) * rs * w4.z + b4.z;
    y[j * 4 + 3] = (v[j * 4 + 3] - mu) * rs * w4.w + b4.w;
  }
  if (FIN == 0) {
    bf16_t* xbo = xbout + (size_t)(bm + row) * 256 + sub * 16;
#pragma unroll
    for (int j = 0; j < 4; ++j) {
      bf16x4 ob;
      ob[0] = (bf16_t)y[j * 4 + 0]; ob[1] = (bf16_t)y[j * 4 + 1];
      ob[2] = (bf16_t)y[j * 4 + 2]; ob[3] = (bf16_t)y[j * 4 + 3];
      ((bf16x4*)xbo)[j] = ob;
    }
  } else {
    float s2 = 0.f;
#pragma unroll
    for (int j = 0; j < 16; ++j) s2 += y[j];
#pragma unroll
    for (int o = 1; o < 16; o <<= 1) s2 += __shfl_xor(s2, o);
    float mu2 = s2 * (1.f / 256.f);
    float q2 = 0.f;
#pragma unroll
    for (int j = 0; j < 16; ++j) { float d = y[j] - mu2; q2 += d * d; }
#pragma unroll
    for (int o = 1; o < 16; o <<= 1) q2 += __shfl_xor(q2, o);
    float rs2 = rsqrtf(q2 * (1.f / 256.f) + 1e-5f);
    float* xo = outf + (size_t)(bm + row) * 256 + sub * 16;
#pragma unroll
    for (int j = 0; j < 4; ++j) {
      float4 w4 = ((const float4*)(lnfw + sub * 16))[j];
      float4 b4 = ((const float4*)(lnfb + sub * 16))[j];
      float4 o4 = {(y[j * 4 + 0] - mu2) * rs2 * w4.x + b4.x,
                   (y[j * 4 + 1] - mu2) * rs2 * w4.y + b4.y,
                   (y[j * 4 + 2] - mu2) * rs2 * w4.z + b4.z,
                   (y[j * 4 + 3] - mu2) * rs2 * w4.w + b4.w};
      ((float4*)xo)[j] = o4;
    }
  }
}

extern "C" void kernel_launch(void* const* d_in, const int* in_sizes, int n_in,
                              void* d_out, int out_size, void* d_ws, size_t ws_size,
                              hipStream_t stream) {
  const float* H    = (const float*)d_in[0];
  const int*   ei   = (const int*)d_in[1];
  const float* m    = (const float*)d_in[2];
  const float* Wqkv = (const float*)d_in[3];
  const float* bqkv = (const float*)d_in[4];
  const float* Wo   = (const float*)d_in[5];
  const float* bo   = (const float*)d_in[6];
  const float* ln1w = (const float*)d_in[7];
  const float* ln1b = (const float*)d_in[8];
  const float* W1   = (const float*)d_in[9];
  const float* b1   = (const float*)d_in[10];
  const float* W2   = (const float*)d_in[11];
  const float* b2   = (const float*)d_in[12];
  const float* ln2w = (const float*)d_in[13];
  const float* ln2b = (const float*)d_in[14];
  const float* lnfw = (const float*)d_in[15];
  const float* lnfb = (const float*)d_in[16];

  char* ws = (char*)d_ws;
  size_t off = 0;
  auto alloc = [&](size_t bytes) {
    void* p = ws + off;
    off += (bytes + 255) & ~(size_t)255;
    return p;
  };

  int*    cnt   = (int*)alloc((size_t)BATCH * NTOK * 4);
  int*    ent   = (int*)alloc((size_t)BATCH * NTOK * CAP * 4);
  int*    nbcol = (int*)alloc((size_t)BATCH * NTOK * CAP * 4);
  float*  nbval = (float*)alloc((size_t)BATCH * NTOK * CAP * 4);
  int*    nbcnt = (int*)alloc((size_t)BATCH * NTOK * 4);
  bf16_t* qkvb  = (bf16_t*)alloc((size_t)8192 * 768 * 2);
  bf16_t* wqkvb = (bf16_t*)alloc((size_t)2 * 768 * 256 * 2);
  bf16_t* wob   = (bf16_t*)alloc((size_t)2 * 256 * 256 * 2);
  bf16_t* w1b   = (bf16_t*)alloc((size_t)2 * 1024 * 256 * 2);
  bf16_t* w2b   = (bf16_t*)alloc((size_t)2 * 256 * 1024 * 2);
  bf16_t* xb    = (bf16_t*)alloc((size_t)8192 * 256 * 2);   // layer input x (bf16)
  bf16_t* x1b   = (bf16_t*)alloc((size_t)8192 * 256 * 2);   // after ln1
  bf16_t* ffb   = (bf16_t*)alloc((size_t)8192 * 1024 * 2);

  k_pre<<<3584, 256, 0, stream>>>((int4*)cnt, H, Wqkv, Wo, W1, W2,
                                  xb, wqkvb, wob, w1b, w2b);
  k_scatter2<<<(BATCH * NEDGE + 255) / 256, 256, 0, stream>>>(ei, cnt, ent);
  k_build2<<<BATCH * NTOK / 4, 256, 0, stream>>>(cnt, ent, m, nbcol, nbval, nbcnt);

  for (int lyr = 0; lyr < 2; ++lyr) {
    gemm_bt<3, 64><<<(768 / 128) * (8192 / 64), 256, 0, stream>>>(
        xb, wqkvb + (size_t)lyr * 768 * 256, bqkv + lyr * 768, qkvb, 8192, 768, 256);
    k_attn_oproj<<<512, 256, 0, stream>>>(
        qkvb, nbcol, nbval, nbcnt,
        wob + (size_t)lyr * 256 * 256, bo + lyr * 256, xb,
        ln1w + lyr * 256, ln1b + lyr * 256, x1b);
    gemm_bt<1, 128><<<(1024 / 128) * (8192 / 128), 256, 0, stream>>>(
        x1b, w1b + (size_t)lyr * 1024 * 256, b1 + lyr * 1024, ffb, 8192, 1024, 256);
    if (lyr == 0) {
      gemm_ln<0><<<512, 256, 0, stream>>>(
          ffb, w2b + (size_t)lyr * 256 * 1024, b2 + lyr * 256, x1b,
          ln2w + lyr * 256, ln2b + lyr * 256, nullptr, nullptr, xb, nullptr, 1024);
    } else {
      gemm_ln<1><<<512, 256, 0, stream>>>(
          ffb, w2b + (size_t)lyr * 256 * 1024, b2 + lyr * 256, x1b,
          ln2w + lyr * 256, ln2b + lyr * 256, lnfw, lnfb, nullptr, (float*)d_out, 1024);
    }
  }
}

// Round 16
// 178.646 us; speedup vs baseline: 1.2986x; 1.0751x over previous
//
#include <hip/hip_runtime.h>
#include <hip/hip_bf16.h>
#include <math.h>

typedef __bf16 bf16_t;
typedef __attribute__((ext_vector_type(8))) __bf16 bf16x8;
typedef __attribute__((ext_vector_type(4))) __bf16 bf16x4;
typedef __attribute__((ext_vector_type(4))) float f32x4;

#define BATCH 8
#define NTOK 1024
#define NEDGE 16384
#define CAP 96   // max entries per row (deg ~ Poisson(32); P(deg>96) < 1e-20)

// ---------------- async global->LDS (16B per lane, wave-uniform LDS base) ----------------
__device__ __forceinline__ void gload_lds16(const void* g, void* l) {
  __builtin_amdgcn_global_load_lds(
      (const __attribute__((address_space(1))) unsigned int*)(uintptr_t)g,
      (__attribute__((address_space(3))) unsigned int*)(unsigned int)(uintptr_t)l,
      16, 0, 0);
}

// ---------------- fused: f32->bf16 cvt for H + weights; blocks <8 also zero cnt ----------------
__global__ void k_pre(int4* __restrict__ cnt,
                      const float* __restrict__ H, const float* __restrict__ Wqkv,
                      const float* __restrict__ Wo, const float* __restrict__ W1,
                      const float* __restrict__ W2, bf16_t* __restrict__ xb,
                      bf16_t* __restrict__ wqkvb, bf16_t* __restrict__ wob,
                      bf16_t* __restrict__ w1b, bf16_t* __restrict__ w2b) {
  int i = blockIdx.x * 256 + threadIdx.x;   // float4-quad index
  if (blockIdx.x < 8) {
    int4 z = {0, 0, 0, 0};
    cnt[i] = z;                             // 8 blocks x 256 x int4 = 8192 ints
  }
  const float* s; bf16_t* d; int off;
  if (i < 524288)      { s = H;    d = xb;    off = i; }
  else if (i < 622592) { s = Wqkv; d = wqkvb; off = i - 524288; }
  else if (i < 655360) { s = Wo;   d = wob;   off = i - 622592; }
  else if (i < 786432) { s = W1;   d = w1b;   off = i - 655360; }
  else if (i < 917504) { s = W2;   d = w2b;   off = i - 786432; }
  else return;
  float4 v = ((const float4*)s)[off];
  bf16x4 o;
  o[0] = (bf16_t)v.x; o[1] = (bf16_t)v.y; o[2] = (bf16_t)v.z; o[3] = (bf16_t)v.w;
  ((bf16x4*)d)[off] = o;
}

// ---------------- edge scatter: packed (prio<<10|col) appended to per-row lists ----------------
__global__ void k_scatter2(const int* __restrict__ ei, int* __restrict__ cnt,
                           int* __restrict__ ent) {
  int idx = blockIdx.x * 256 + threadIdx.x;
  if (idx >= BATCH * NEDGE) return;
  int b = idx >> 14;
  int e = idx & (NEDGE - 1);
  const int* eb = ei + (size_t)b * 2 * NEDGE;
  int r = eb[e], c = eb[NEDGE + e];
  int rowr = (b << 10) + r, rowc = (b << 10) + c;
  int q = atomicAdd(cnt + rowr, 1);
  if (q < CAP) ent[rowr * CAP + q] = ((e + 1) << 10) | c;
  q = atomicAdd(cnt + rowc, 1);
  if (q < CAP) ent[rowc * CAP + q] = ((NEDGE + e + 1) << 10) | r;
}

// ---------------- CSR build v2: dedup per row in LDS, canonical ascending-col order ----------------
__global__ __launch_bounds__(256) void k_build2(
    const int* __restrict__ cnt, const int* __restrict__ ent,
    const float* __restrict__ mptr,
    int* __restrict__ nbcol, float* __restrict__ nbval, int* __restrict__ nbcnt) {
  const int w = threadIdx.x >> 6;
  const int l = threadIdx.x & 63;
  const int row = blockIdx.x * 4 + w;   // b*1024 + i
  const int i = row & 1023;
  const int b = row >> 10;
  __shared__ int sE[4][CAP];
  __shared__ int sW[4][CAP];
  const int n = min(cnt[row], CAP);
  for (int j = l; j < n; j += 64) sE[w][j] = ent[(size_t)row * CAP + j];
  __syncthreads();

  bool dcov_l = false;
  bool win[2] = {false, false};
  int myc[2], myp[2];
#pragma unroll
  for (int s = 0; s < 2; ++s) {
    int k = s * 64 + l;
    if (k < n) {
      int pk = sE[w][k], ck = pk & 1023;
      myc[s] = ck; myp[s] = pk;
      bool wn = true;
      for (int j = 0; j < n; ++j) {
        int pj = sE[w][j];
        if ((pj & 1023) == ck && pj > pk) wn = false;
      }
      win[s] = wn;
      sW[w][k] = wn ? 1 : 0;
      if (ck == i) dcov_l = true;
    }
  }
  const bool dcov = __any(dcov_l);
  unsigned long long m0 = __ballot(win[0]);
  unsigned long long m1 = __ballot(win[1]);
  if (l == 0) nbcnt[row] = __popcll(m0) + __popcll(m1) + (dcov ? 0 : 1);

#pragma unroll
  for (int s = 0; s < 2; ++s) {
    int k = s * 64 + l;
    if (k < n && win[s]) {
      int pos = 0;
      for (int j = 0; j < n; ++j)
        if (sW[w][j] && (sE[w][j] & 1023) < myc[s]) ++pos;
      if (!dcov && i < myc[s]) ++pos;
      int e = ((myp[s] >> 10) - 1) & (NEDGE - 1);
      float v = logf(mptr[(size_t)b * NEDGE + e] + 1e-9f);
      if (pos < CAP) {
        nbcol[(size_t)row * CAP + pos] = myc[s];
        nbval[(size_t)row * CAP + pos] = v;
      }
    }
  }
  if (!dcov && l == 0) {   // virtual diagonal (value 0)
    int pos = 0;
    for (int j = 0; j < n; ++j)
      if (sW[w][j] && (sE[w][j] & 1023) < i) ++pos;
    nbcol[(size_t)row * CAP + pos] = i;
    nbval[(size_t)row * CAP + pos] = 0.f;
  }
}

// ---------------- GEMM BMx128 tile, dbuf LDS, race-free single-barrier pipeline ----------------
// 1-D grid + XCD-contiguous swizzle. loop: stage(t+1) -> compute(t) -> vmcnt(0) -> barrier.
// EPI 1: gelu -> bf16 out. EPI 3: plain bf16 out.  BM in {64,128}.
template <int EPI, int BM>
__global__ __launch_bounds__(256) void gemm_bt(
    const bf16_t* __restrict__ A, const bf16_t* __restrict__ Bw,
    const float* __restrict__ bias, bf16_t* __restrict__ Cb,
    int M, int N, int K) {
  constexpr int MI = BM / 32;            // acc rows per wave
  __shared__ bf16_t As[2][BM * 64];
  __shared__ bf16_t Bs[2][128 * 64];
  const int t = threadIdx.x;
  const int l = t & 63;
  const int w = t >> 6;
  const int wr = w >> 1, wc = w & 1;     // 2x2 waves over BM rows x 128 cols
  const int per = gridDim.x >> 3;
  const int g2 = (blockIdx.x & 7) * per + (blockIdx.x >> 3);
  const int NX = N >> 7;                 // N/128 column tiles
  const int bm = (g2 / NX) * BM, bn = (g2 % NX) * 128;

  f32x4 acc[MI][4] = {};

  auto stage = [&](int buf, int k0) {
#pragma unroll
    for (int i = 0; i < BM / 32; ++i) {  // A: BM x 64 elems
      int idx = i * 2048 + t * 8;
      int row = idx >> 6, col = idx & 63;
      gload_lds16(A + (size_t)(bm + row) * K + (k0 + col), (void*)(&As[buf][0] + i * 2048 + w * 512));
    }
#pragma unroll
    for (int i = 0; i < 4; ++i) {        // B: 128 x 64 elems
      int idx = i * 2048 + t * 8;
      int row = idx >> 6, col = idx & 63;
      gload_lds16(Bw + (size_t)(bn + row) * K + (k0 + col), (void*)(&Bs[buf][0] + i * 2048 + w * 512));
    }
  };

  const int nt = K >> 6;
  stage(0, 0);
  asm volatile("s_waitcnt vmcnt(0)" ::: "memory");
  __syncthreads();
  for (int kt = 0; kt < nt; ++kt) {
    const int cur = kt & 1;
    if (kt + 1 < nt) stage(cur ^ 1, (kt + 1) << 6);   // loads fly during compute
#pragma unroll
    for (int kk = 0; kk < 2; ++kk) {
      bf16x8 af[MI], bfr[4];
#pragma unroll
      for (int mi = 0; mi < MI; ++mi)
        af[mi] = *(const bf16x8*)(&As[cur][0] + (wr * (BM / 2) + mi * 16 + (l & 15)) * 64 + kk * 32 + (l >> 4) * 8);
#pragma unroll
      for (int ni = 0; ni < 4; ++ni)
        bfr[ni] = *(const bf16x8*)(&Bs[cur][0] + (wc * 64 + ni * 16 + (l & 15)) * 64 + kk * 32 + (l >> 4) * 8);
#pragma unroll
      for (int mi = 0; mi < MI; ++mi)
#pragma unroll
        for (int ni = 0; ni < 4; ++ni)
          acc[mi][ni] = __builtin_amdgcn_mfma_f32_16x16x32_bf16(af[mi], bfr[ni], acc[mi][ni], 0, 0, 0);
    }
    asm volatile("s_waitcnt vmcnt(0)" ::: "memory");
    __syncthreads();
  }

  const int r0 = (l >> 4) * 4;   // C/D: row=(lane>>4)*4+reg, col=lane&15
  const int cc = l & 15;
#pragma unroll
  for (int mi = 0; mi < MI; ++mi) {
#pragma unroll
    for (int ni = 0; ni < 4; ++ni) {
      int col = bn + wc * 64 + ni * 16 + cc;
      float bv = bias[col];
#pragma unroll
      for (int r = 0; r < 4; ++r) {
        int row = bm + wr * (BM / 2) + mi * 16 + r0 + r;
        float v = acc[mi][ni][r] + bv;
        if (EPI == 1)
          v = 0.5f * v * (1.f + erff(v * 0.70710678118654752f));   // exact GELU
        Cb[(size_t)row * N + col] = (bf16_t)v;
      }
    }
  }
}

// ---------------- fused attention + out-projection + residual + LN1, BM=8 ----------------
// grid 1024 (XCD-swizzled: batch = bid&7) -> 4 blocks/CU (36.1 KB LDS), 16 waves/CU during
// the latency-bound K/V gather. Wave w: rows bm+w*2..+1 serial. oproj: Wo staged [256][32]
// K-tiles (8 steps, same K order); MFMA computes 16 rows, writes valid rows 0-7 only.
__global__ __launch_bounds__(256) void k_attn_oproj(
    const bf16_t* __restrict__ qkvb,
    const int* __restrict__ nbcol, const float* __restrict__ nbval,
    const int* __restrict__ nbcnt,
    const bf16_t* __restrict__ Wo, const float* __restrict__ bo,
    const bf16_t* __restrict__ residb,
    const float* __restrict__ lnw, const float* __restrict__ lnb,
    bf16_t* __restrict__ xbout) {
  __shared__ __align__(16) char smem[36096];
  bf16_t* Bs    = (bf16_t*)smem;             // [256][32] Wo k-tile (16384 B)
  bf16_t* ao    = (bf16_t*)(smem + 16384);   // [8][264] attn out (4224 B)
  float*  s_s   = (float*)(smem + 20608);    // [4][8][97] scores (12416 B)
  int*    s_col = (int*)(smem + 33024);      // [4][96]
  float*  s_bia = (float*)(smem + 34560);    // [4][96] (end 36096)
  float*  E     = (float*)(smem + 16384);    // [16][258] f32 over ao+s_s (dead after oproj)
  const int t = threadIdx.x, l = t & 63, w = t >> 6;
  const int b = blockIdx.x & 7;              // XCD-swizzle: one batch per XCD
  const int bm = (b << 10) + (blockIdx.x >> 3) * 8;

  auto stageB = [&](int k0) {                // [256][32] tile: 4 issues/wave, 16x32 window each
#pragma unroll
    for (int i = 0; i < 4; ++i) {
      int rr = (w * 4 + i) * 16 + (l >> 2), ch = (l & 3) * 8;   // LDS off = l*16B matches
      gload_lds16(Wo + (size_t)rr * 256 + (k0 + ch), (void*)(Bs + (w * 4 + i) * 512));
    }
  };
  stageB(0);   // Wo tile 0 flies during the whole attention phase

  const float scale = 0.17677669529663687f;   // 1/sqrt(32)
  const int h1 = l & 7;
  for (int rr = 0; rr < 2; ++rr) {
    const int row = bm + w * 2 + rr;
    const int deg = nbcnt[row];
    asm volatile("s_waitcnt lgkmcnt(0)" ::: "memory");
    for (int j = l; j < deg; j += 64) {
      s_col[w * 96 + j] = nbcol[(size_t)row * CAP + j];
      s_bia[w * 96 + j] = nbval[(size_t)row * CAP + j];
    }
    float q[32];
    {
      const bf16x8* qp = (const bf16x8*)(qkvb + (size_t)row * 768 + h1 * 32);
#pragma unroll
      for (int u = 0; u < 4; ++u) {
        bf16x8 t8 = qp[u];
#pragma unroll
        for (int j = 0; j < 8; ++j) q[u * 8 + j] = (float)t8[j];
      }
    }
    asm volatile("s_waitcnt lgkmcnt(0)" ::: "memory");

    const int nit = (deg + 7) >> 3;
    float mx = -INFINITY;
    for (int it = 0; it < nit; ++it) {
      int idx = it * 8 + (l >> 3);
      float sc = -INFINITY;
      if (idx < deg) {
        int col = s_col[w * 96 + idx];
        const bf16x8* kr = (const bf16x8*)(qkvb + ((size_t)((b << 10) + col)) * 768 + 256 + h1 * 32);
        float d = 0.f;
#pragma unroll
        for (int u = 0; u < 4; ++u) {
          bf16x8 kv = kr[u];
#pragma unroll
          for (int j = 0; j < 8; ++j) d += (float)kv[j] * q[u * 8 + j];
        }
        sc = d * scale + s_bia[w * 96 + idx];
        s_s[(w * 8 + h1) * 97 + idx] = sc;
      }
      mx = fmaxf(mx, sc);
    }
#pragma unroll
    for (int o = 8; o < 64; o <<= 1) mx = fmaxf(mx, __shfl_xor(mx, o));
    asm volatile("s_waitcnt lgkmcnt(0)" ::: "memory");
    float lsum = 0.f;
    for (int it = 0; it < nit; ++it) {
      int idx = it * 8 + (l >> 3);
      if (idx < deg) {
        float p = __expf(s_s[(w * 8 + h1) * 97 + idx] - mx);
        s_s[(w * 8 + h1) * 97 + idx] = p;
        lsum += p;
      }
    }
#pragma unroll
    for (int o = 8; o < 64; o <<= 1) lsum += __shfl_xor(lsum, o);
    const int h3 = l >> 3;
    float den = __shfl(lsum, h3);
    asm volatile("s_waitcnt lgkmcnt(0)" ::: "memory");
    float a0 = 0.f, a1 = 0.f, a2 = 0.f, a3 = 0.f;
    const bf16_t* vbase = qkvb + ((size_t)(b << 10)) * 768 + 512 + l * 4;
#pragma unroll 4
    for (int idx = 0; idx < deg; ++idx) {
      float p = s_s[(w * 8 + h3) * 97 + idx];
      bf16x4 vv = *(const bf16x4*)(vbase + (size_t)s_col[w * 96 + idx] * 768);
      a0 += p * (float)vv[0]; a1 += p * (float)vv[1];
      a2 += p * (float)vv[2]; a3 += p * (float)vv[3];
    }
    float rden = 1.f / den;
    bf16x4 o4;
    o4[0] = (bf16_t)(a0 * rden); o4[1] = (bf16_t)(a1 * rden);
    o4[2] = (bf16_t)(a2 * rden); o4[3] = (bf16_t)(a3 * rden);
    *(bf16x4*)(ao + (w * 2 + rr) * 264 + l * 4) = o4;
  }
  asm volatile("s_waitcnt vmcnt(0) lgkmcnt(0)" ::: "memory");
  __syncthreads();

  // oproj: C[8][256] = ao @ Wo^T, K=256 in 8 tiles of 32 (same K order as kk-split 64s)
  f32x4 acc[4] = {};
  for (int kt = 0; kt < 8; ++kt) {
    bf16x8 af = *(const bf16x8*)(ao + (l & 15) * 264 + kt * 32 + (l >> 4) * 8);
    __builtin_amdgcn_s_setprio(1);
#pragma unroll
    for (int ni = 0; ni < 4; ++ni) {
      bf16x8 bfr = *(const bf16x8*)(Bs + (w * 64 + ni * 16 + (l & 15)) * 32 + (l >> 4) * 8);
      acc[ni] = __builtin_amdgcn_mfma_f32_16x16x32_bf16(af, bfr, acc[ni], 0, 0, 0);
    }
    __builtin_amdgcn_s_setprio(0);
    __syncthreads();                       // all ao/Bs reads of this step done
    if (kt < 7) {
      stageB((kt + 1) * 32);
      asm volatile("s_waitcnt vmcnt(0)" ::: "memory");
      __syncthreads();
    }
  }

  // stash C+bias into E [16][258] (rows 8-15 garbage, never read); E aliases ao (dead)
  const int r0 = (l >> 4) * 4;
  const int cc = l & 15;
#pragma unroll
  for (int ni = 0; ni < 4; ++ni) {
    int col = w * 64 + ni * 16 + cc;
    float bv = bo[col];
#pragma unroll
    for (int r = 0; r < 4; ++r)
      E[(r0 + r) * 258 + col] = acc[ni][r] + bv;
  }
  __syncthreads();

  // residual + LN: 32 threads/row, rows 0-7, 8 cols/thread
  const int row = t >> 5;
  const int sub = t & 31;
  const float* ep = E + row * 258 + sub * 8;
  const bf16_t* rp = residb + (size_t)(bm + row) * 256 + sub * 8;
  float v[8];
  float s = 0.f;
#pragma unroll
  for (int j = 0; j < 2; ++j) {
    float4 a4 = ((const float4*)ep)[j];
    bf16x4 r4 = ((const bf16x4*)rp)[j];
    v[j * 4 + 0] = a4.x + (float)r4[0]; v[j * 4 + 1] = a4.y + (float)r4[1];
    v[j * 4 + 2] = a4.z + (float)r4[2]; v[j * 4 + 3] = a4.w + (float)r4[3];
    s += v[j * 4 + 0] + v[j * 4 + 1] + v[j * 4 + 2] + v[j * 4 + 3];
  }
#pragma unroll
  for (int o = 1; o < 32; o <<= 1) s += __shfl_xor(s, o);
  float mu = s * (1.f / 256.f);
  float e2 = 0.f;
#pragma unroll
  for (int j = 0; j < 8; ++j) { float d = v[j] - mu; e2 += d * d; }
#pragma unroll
  for (int o = 1; o < 32; o <<= 1) e2 += __shfl_xor(e2, o);
  float rs = rsqrtf(e2 * (1.f / 256.f) + 1e-5f);
  bf16_t* xbo = xbout + (size_t)(bm + row) * 256 + sub * 8;
#pragma unroll
  for (int j = 0; j < 2; ++j) {
    float4 w4 = ((const float4*)(lnw + sub * 8))[j];
    float4 b4 = ((const float4*)(lnb + sub * 8))[j];
    bf16x4 ob;
    ob[0] = (bf16_t)((v[j * 4 + 0] - mu) * rs * w4.x + b4.x);
    ob[1] = (bf16_t)((v[j * 4 + 1] - mu) * rs * w4.y + b4.y);
    ob[2] = (bf16_t)((v[j * 4 + 2] - mu) * rs * w4.z + b4.z);
    ob[3] = (bf16_t)((v[j * 4 + 3] - mu) * rs * w4.w + b4.w);
    ((bf16x4*)xbo)[j] = ob;
  }
}

// ---------------- fused GEMM(BM=16, BN=256) + bias + bf16-residual + LayerNorm ----------------
// XCD-contiguous row-tile swizzle; race-free pipeline.
// FIN=0: bf16 xbout. FIN=1: additionally lnf(y) -> f32 outf (d_out).
template <int FIN>
__global__ __launch_bounds__(256) void gemm_ln(
    const bf16_t* __restrict__ A, const bf16_t* __restrict__ Bw,
    const float* __restrict__ bias, const bf16_t* __restrict__ residb,
    const float* __restrict__ lnw, const float* __restrict__ lnb,
    const float* __restrict__ lnfw, const float* __restrict__ lnfb,
    bf16_t* __restrict__ xbout, float* __restrict__ outf, int K) {
  __shared__ __align__(16) char smem[69632];
  bf16_t* As = (bf16_t*)smem;             // [2][16][64] = 4KB
  bf16_t* Bs = (bf16_t*)(smem + 4096);    // [2][256][64] = 64KB
  float*  E  = (float*)smem;              // epi: [16][258] f32 (aliases, after barrier)
  const int t = threadIdx.x;
  const int l = t & 63;
  const int w = t >> 6;
  const int per = gridDim.x >> 3;
  const int g2 = (blockIdx.x & 7) * per + (blockIdx.x >> 3);   // XCD-contiguous rows
  const int bm = g2 * 16;

  f32x4 acc[4] = {};

  auto stage = [&](int buf, int k0) {
    if (w < 2) {
      int row = w * 8 + (l >> 3), col = (l & 7) * 8;
      gload_lds16(A + (size_t)(bm + row) * K + (k0 + col), (void*)(As + buf * 1024 + w * 512));
    }
#pragma unroll
    for (int i = 0; i < 8; ++i) {
      int rr = (w * 8 + i) * 8 + (l >> 3), col = (l & 7) * 8;
      gload_lds16(Bw + (size_t)rr * K + (k0 + col), (void*)(Bs + buf * 16384 + (w * 8 + i) * 512));
    }
  };

  const int nt = K >> 6;
  stage(0, 0);
  asm volatile("s_waitcnt vmcnt(0)" ::: "memory");
  __syncthreads();
  for (int kt = 0; kt < nt; ++kt) {
    const int cur = kt & 1;
    if (kt + 1 < nt) stage(cur ^ 1, (kt + 1) << 6);
#pragma unroll
    for (int kk = 0; kk < 2; ++kk) {
      bf16x8 af = *(const bf16x8*)(As + cur * 1024 + (l & 15) * 64 + kk * 32 + (l >> 4) * 8);
#pragma unroll
      for (int ni = 0; ni < 4; ++ni) {
        bf16x8 bfr = *(const bf16x8*)(Bs + cur * 16384 + (w * 64 + ni * 16 + (l & 15)) * 64 + kk * 32 + (l >> 4) * 8);
        acc[ni] = __builtin_amdgcn_mfma_f32_16x16x32_bf16(af, bfr, acc[ni], 0, 0, 0);
      }
    }
    asm volatile("s_waitcnt vmcnt(0)" ::: "memory");
    __syncthreads();
  }

  const int r0 = (l >> 4) * 4;
  const int cc = l & 15;
#pragma unroll
  for (int ni = 0; ni < 4; ++ni) {
    int col = w * 64 + ni * 16 + cc;
    float bv = bias[col];
#pragma unroll
    for (int r = 0; r < 4; ++r)
      E[(r0 + r) * 258 + col] = acc[ni][r] + bv;
  }
  __syncthreads();

  const int row = t >> 4;
  const int sub = t & 15;
  const float* ep = E + row * 258 + sub * 16;
  const bf16_t* rp = residb + (size_t)(bm + row) * 256 + sub * 16;
  float v[16];
  float s = 0.f;
#pragma unroll
  for (int j = 0; j < 4; ++j) {
    float4 a4 = ((const float4*)ep)[j];
    bf16x4 r4 = ((const bf16x4*)rp)[j];
    v[j * 4 + 0] = a4.x + (float)r4[0]; v[j * 4 + 1] = a4.y + (float)r4[1];
    v[j * 4 + 2] = a4.z + (float)r4[2]; v[j * 4 + 3] = a4.w + (float)r4[3];
    s += v[j * 4 + 0] + v[j * 4 + 1] + v[j * 4 + 2] + v[j * 4 + 3];
  }
#pragma unroll
  for (int o = 1; o < 16; o <<= 1) s += __shfl_xor(s, o);
  float mu = s * (1.f / 256.f);
  float e2 = 0.f;
#pragma unroll
  for (int j = 0; j < 16; ++j) { float d = v[j] - mu; e2 += d * d; }
#pragma unroll
  for (int o = 1; o < 16; o <<= 1) e2 += __shfl_xor(e2, o);
  float rs = rsqrtf(e2 * (1.f / 256.f) + 1e-5f);
  float y[16];
#pragma unroll
  for (int j = 0; j < 4; ++j) {
    float4 w4 = ((const float4*)(lnw + sub * 16))[j];
    float4 b4 = ((const float4*)(lnb + sub * 16))[j];
    y[j * 4 + 0] = (v[j * 4 + 0] - mu) * rs * w4.x + b4.x;
    y[j * 4 + 1] = (v[j * 4 + 1] - mu) * rs * w4.y + b4.y;
    y[j * 4 + 2] = (v[j * 4 + 2] - mu) * rs * w4.z + b4.z;
    y[j * 4 + 3] = (v[j * 4 + 3] - mu) * rs * w4.w + b4.w;
  }
  if (FIN == 0) {
    bf16_t* xbo = xbout + (size_t)(bm + row) * 256 + sub * 16;
#pragma unroll
    for (int j = 0; j < 4; ++j) {
      bf16x4 ob;
      ob[0] = (bf16_t)y[j * 4 + 0]; ob[1] = (bf16_t)y[j * 4 + 1];
      ob[2] = (bf16_t)y[j * 4 + 2]; ob[3] = (bf16_t)y[j * 4 + 3];
      ((bf16x4*)xbo)[j] = ob;
    }
  } else {
    float s2 = 0.f;
#pragma unroll
    for (int j = 0; j < 16; ++j) s2 += y[j];
#pragma unroll
    for (int o = 1; o < 16; o <<= 1) s2 += __shfl_xor(s2, o);
    float mu2 = s2 * (1.f / 256.f);
    float q2 = 0.f;
#pragma unroll
    for (int j = 0; j < 16; ++j) { float d = y[j] - mu2; q2 += d * d; }
#pragma unroll
    for (int o = 1; o < 16; o <<= 1) q2 += __shfl_xor(q2, o);
    float rs2 = rsqrtf(q2 * (1.f / 256.f) + 1e-5f);
    float* xo = outf + (size_t)(bm + row) * 256 + sub * 16;
#pragma unroll
    for (int j = 0; j < 4; ++j) {
      float4 w4 = ((const float4*)(lnfw + sub * 16))[j];
      float4 b4 = ((const float4*)(lnfb + sub * 16))[j];
      float4 o4 = {(y[j * 4 + 0] - mu2) * rs2 * w4.x + b4.x,
                   (y[j * 4 + 1] - mu2) * rs2 * w4.y + b4.y,
                   (y[j * 4 + 2] - mu2) * rs2 * w4.z + b4.z,
                   (y[j * 4 + 3] - mu2) * rs2 * w4.w + b4.w};
      ((float4*)xo)[j] = o4;
    }
  }
}

extern "C" void kernel_launch(void* const* d_in, const int* in_sizes, int n_in,
                              void* d_out, int out_size, void* d_ws, size_t ws_size,
                              hipStream_t stream) {
  const float* H    = (const float*)d_in[0];
  const int*   ei   = (const int*)d_in[1];
  const float* m    = (const float*)d_in[2];
  const float* Wqkv = (const float*)d_in[3];
  const float* bqkv = (const float*)d_in[4];
  const float* Wo   = (const float*)d_in[5];
  const float* bo   = (const float*)d_in[6];
  const float* ln1w = (const float*)d_in[7];
  const float* ln1b = (const float*)d_in[8];
  const float* W1   = (const float*)d_in[9];
  const float* b1   = (const float*)d_in[10];
  const float* W2   = (const float*)d_in[11];
  const float* b2   = (const float*)d_in[12];
  const float* ln2w = (const float*)d_in[13];
  const float* ln2b = (const float*)d_in[14];
  const float* lnfw = (const float*)d_in[15];
  const float* lnfb = (const float*)d_in[16];

  char* ws = (char*)d_ws;
  size_t off = 0;
  auto alloc = [&](size_t bytes) {
    void* p = ws + off;
    off += (bytes + 255) & ~(size_t)255;
    return p;
  };

  int*    cnt   = (int*)alloc((size_t)BATCH * NTOK * 4);
  int*    ent   = (int*)alloc((size_t)BATCH * NTOK * CAP * 4);
  int*    nbcol = (int*)alloc((size_t)BATCH * NTOK * CAP * 4);
  float*  nbval = (float*)alloc((size_t)BATCH * NTOK * CAP * 4);
  int*    nbcnt = (int*)alloc((size_t)BATCH * NTOK * 4);
  bf16_t* qkvb  = (bf16_t*)alloc((size_t)8192 * 768 * 2);
  bf16_t* wqkvb = (bf16_t*)alloc((size_t)2 * 768 * 256 * 2);
  bf16_t* wob   = (bf16_t*)alloc((size_t)2 * 256 * 256 * 2);
  bf16_t* w1b   = (bf16_t*)alloc((size_t)2 * 1024 * 256 * 2);
  bf16_t* w2b   = (bf16_t*)alloc((size_t)2 * 256 * 1024 * 2);
  bf16_t* xb    = (bf16_t*)alloc((size_t)8192 * 256 * 2);   // layer input x (bf16)
  bf16_t* x1b   = (bf16_t*)alloc((size_t)8192 * 256 * 2);   // after ln1
  bf16_t* ffb   = (bf16_t*)alloc((size_t)8192 * 1024 * 2);

  k_pre<<<3584, 256, 0, stream>>>((int4*)cnt, H, Wqkv, Wo, W1, W2,
                                  xb, wqkvb, wob, w1b, w2b);
  k_scatter2<<<(BATCH * NEDGE + 255) / 256, 256, 0, stream>>>(ei, cnt, ent);
  k_build2<<<BATCH * NTOK / 4, 256, 0, stream>>>(cnt, ent, m, nbcol, nbval, nbcnt);

  for (int lyr = 0; lyr < 2; ++lyr) {
    gemm_bt<3, 64><<<(768 / 128) * (8192 / 64), 256, 0, stream>>>(
        xb, wqkvb + (size_t)lyr * 768 * 256, bqkv + lyr * 768, qkvb, 8192, 768, 256);
    k_attn_oproj<<<1024, 256, 0, stream>>>(
        qkvb, nbcol, nbval, nbcnt,
        wob + (size_t)lyr * 256 * 256, bo + lyr * 256, xb,
        ln1w + lyr * 256, ln1b + lyr * 256, x1b);
    gemm_bt<1, 128><<<(1024 / 128) * (8192 / 128), 256, 0, stream>>>(
        x1b, w1b + (size_t)lyr * 1024 * 256, b1 + lyr * 1024, ffb, 8192, 1024, 256);
    if (lyr == 0) {
      gemm_ln<0><<<512, 256, 0, stream>>>(
          ffb, w2b + (size_t)lyr * 256 * 1024, b2 + lyr * 256, x1b,
          ln2w + lyr * 256, ln2b + lyr * 256, nullptr, nullptr, xb, nullptr, 1024);
    } else {
      gemm_ln<1><<<512, 256, 0, stream>>>(
          ffb, w2b + (size_t)lyr * 256 * 1024, b2 + lyr * 256, x1b,
          ln2w + lyr * 256, ln2b + lyr * 256, lnfw, lnfb, nullptr, (float*)d_out, 1024);
    }
  }
}